// Round 8
// baseline (37296.854 us; speedup 1.0000x reference)
//
#include <hip/hip_runtime.h>
#include <math.h>

#define B_SZ 128
#define T_IN 8000
#define T_OUT 1600
#define HDIM 384
#define GDIM 1536   // 4*H
#define TC 40       // time chunk
#define NCHUNK (T_OUT / TC)   // 40
#define NTILES (12 * (B_SZ * TC / 128))   // 480 gemm tiles per chunk
#define NLB 64            // LSTM blocks: 16 groups x 4 column-slices

typedef _Float16 f16;
typedef __attribute__((ext_vector_type(2))) _Float16 f16x2;
typedef __attribute__((ext_vector_type(4))) _Float16 f16x4;
typedef __attribute__((ext_vector_type(8))) _Float16 f16x8;
typedef __attribute__((ext_vector_type(4))) float f32x4;
typedef __attribute__((ext_vector_type(4))) unsigned int u32x4;

__device__ inline float fdot2(f16x2 a, f16x2 b, float c) {
#if __has_builtin(__builtin_amdgcn_fdot2)
  return __builtin_amdgcn_fdot2(a, b, c, false);
#else
  return fmaf((float)a[0], (float)b[0], fmaf((float)a[1], (float)b[1], c));
#endif
}

__device__ inline float rcp_fast(float x) {
#if __has_builtin(__builtin_amdgcn_rcpf)
  return __builtin_amdgcn_rcpf(x);
#else
  return 1.f / x;
#endif
}
__device__ inline float sigf(float z) { return rcp_fast(1.f + __expf(-z)); }
__device__ inline float tanh_fast(float z) {
  z = fminf(fmaxf(z, -15.f), 15.f);
  float e = __expf(2.f * z);
  return (e - 1.f) * rcp_fast(e + 1.f);
}

// ---------------------------------------------------------------------------
// conv1 (5,1,4) + silu + conv2 (5,4,16) + silu, fused. One thread per (b,t).
// ---------------------------------------------------------------------------
__global__ __launch_bounds__(256) void conv12_kernel(
    const float* __restrict__ x, const float* __restrict__ w1, const float* __restrict__ b1,
    const float* __restrict__ w2, const float* __restrict__ b2, f16* __restrict__ y2) {
  __shared__ float sw1[20], sb1[4], sw2[320], sb2[16];
  int tid = threadIdx.x;
  if (tid < 20) sw1[tid] = w1[tid];
  if (tid < 4)  sb1[tid] = b1[tid];
  if (tid < 16) sb2[tid] = b2[tid];
  for (int i = tid; i < 320; i += 256) sw2[i] = w2[i];
  __syncthreads();
  int flat = blockIdx.x * 256 + tid;
  int b = flat / T_IN, t = flat % T_IN;
  const float* xb = x + (size_t)b * T_IN;
  float xv[9];
#pragma unroll
  for (int d = 0; d < 9; ++d) {
    int tt = t + d - 4;
    xv[d] = (tt >= 0 && tt < T_IN) ? xb[tt] : 0.f;
  }
  float y1[5][4];
#pragma unroll
  for (int u = 0; u < 5; ++u) {
    int tau = t + u - 2;
    bool valid = (tau >= 0 && tau < T_IN);
#pragma unroll
    for (int co = 0; co < 4; ++co) {
      float a = sb1[co];
#pragma unroll
      for (int k = 0; k < 5; ++k) a = fmaf(xv[u + k], sw1[k * 4 + co], a);
      y1[u][co] = valid ? (a / (1.f + expf(-a))) : 0.f;
    }
  }
  f16x8 o0, o1;
#pragma unroll
  for (int co = 0; co < 16; ++co) {
    float a = sb2[co];
#pragma unroll
    for (int u = 0; u < 5; ++u)
#pragma unroll
      for (int ci = 0; ci < 4; ++ci)
        a = fmaf(y1[u][ci], sw2[(u * 4 + ci) * 16 + co], a);
    float sv = a / (1.f + expf(-a));
    if (co < 8) o0[co] = (f16)sv; else o1[co - 8] = (f16)sv;
  }
  f16x8* dst = (f16x8*)(y2 + (size_t)flat * 16);
  dst[0] = o0;
  dst[1] = o1;
}

// ---------------------------------------------------------------------------
// w3 -> transposed f16 [c][k] (K padded 304->320 with zeros).
// ---------------------------------------------------------------------------
__global__ __launch_bounds__(256) void w3cvt_kernel(
    const float* __restrict__ w3, f16* __restrict__ w3t) {
  int idx = blockIdx.x * 256 + threadIdx.x;   // 384*320 = 122880
  int c = idx / 320, k = idx - c * 320;
  w3t[idx] = (k < 304) ? (f16)w3[(size_t)k * 384 + c] : (f16)0.f;
}

// ---------------------------------------------------------------------------
// conv3 via MFMA (verified round 6): per block one batch, 32 t-outputs x 384
// ch, K=320 (19 taps x 16 ch, zero-padded). Fragment mappings identical to
// the verified LSTM MFMA usage. in_s padded to 24 f16/row, bs_t to 40.
// ---------------------------------------------------------------------------
#define C3M 32
#define C3K 320
#define INSP 24
#define BSTP 40

__global__ __launch_bounds__(384) void conv3_kernel(
    const f16* __restrict__ y2, const f16* __restrict__ w3t,
    const float* __restrict__ b3, f16* __restrict__ act) {
  __shared__ f16 in_s[176 * INSP];
  __shared__ f16 bs_t[384 * BSTP];
  int tid = threadIdx.x;
  int b = blockIdx.y;
  int t0 = blockIdx.x * C3M;
  int base_t = t0 * 5 - 7;
  for (int j = tid; j < 352; j += 384) {
    int tau = j >> 1, ci0 = (j & 1) * 8;
    int tt = base_t + tau;
    f16x8 v = {};
    if (tt >= 0 && tt < T_IN)
      v = *(const f16x8*)(y2 + ((size_t)b * T_IN + tt) * 16 + ci0);
    *(f16x8*)&in_s[tau * INSP + ci0] = v;
  }
  int wv = tid >> 6;       // wave 0..5 -> N-tiles wv*4..wv*4+3
  int l = tid & 63;
  int lm = l & 15;
  int lk = l >> 4;
  f32x4 acc[2][4];
#pragma unroll
  for (int mt = 0; mt < 2; ++mt)
#pragma unroll
    for (int q = 0; q < 4; ++q) acc[mt][q] = (f32x4){0.f, 0.f, 0.f, 0.f};
  for (int ks = 0; ks < 10; ++ks) {
    __syncthreads();
    for (int u = tid; u < 1536; u += 384) {
      int c = u >> 2, k8 = u & 3;
      *(f16x8*)&bs_t[c * BSTP + k8 * 8] =
          *(const f16x8*)(w3t + (size_t)c * C3K + ks * 32 + k8 * 8);
    }
    __syncthreads();
    int kg = ks * 32 + lk * 8;
    int kk = kg >> 4, ci = kg & 15;
    f16x8 a0 = *(const f16x8*)&in_s[(lm * 5 + kk) * INSP + ci];
    f16x8 a1 = *(const f16x8*)&in_s[((lm + 16) * 5 + kk) * INSP + ci];
#pragma unroll
    for (int q = 0; q < 4; ++q) {
      f16x8 bf = *(const f16x8*)&bs_t[((wv * 4 + q) * 16 + lm) * BSTP + lk * 8];
      acc[0][q] = __builtin_amdgcn_mfma_f32_16x16x32_f16(a0, bf, acc[0][q], 0, 0, 0);
      acc[1][q] = __builtin_amdgcn_mfma_f32_16x16x32_f16(a1, bf, acc[1][q], 0, 0, 0);
    }
  }
#pragma unroll
  for (int mt = 0; mt < 2; ++mt)
#pragma unroll
    for (int q = 0; q < 4; ++q) {
      int n = (wv * 4 + q) * 16 + lm;
      float bv = b3[n];
#pragma unroll
      for (int r = 0; r < 4; ++r) {
        int m = mt * 16 + lk * 4 + r;
        float a = acc[mt][q][r] + bv;
        a = a / (1.f + expf(-a));
        act[((size_t)b * T_OUT + t0 + m) * HDIM + n] = (f16)a;
      }
    }
}

// ---------------------------------------------------------------------------
// Wh -> MFMA B-fragment repack (4-slice layout).
// whB dword idx = ((((L*4+isl)*24+nt)*12+ks)*64 + lane)*4 + d
//   cz = nt*16 + (lane&15); gate = cz&3; jj = cz>>2 in [0,96)
//   gcol = gate*384 + isl*96 + jj
//   k2d = ks*16 + (lane>>4)*4 + d;  pair = (Wh[2*k2d][gcol], Wh[2*k2d+1][gcol])
// ---------------------------------------------------------------------------
__global__ __launch_bounds__(256) void whcvt_kernel(
    const float* __restrict__ Wh, f16x2* __restrict__ whB) {
  size_t idx = (size_t)blockIdx.x * 256 + threadIdx.x;
  int d = (int)(idx & 3);
  size_t r1 = idx >> 2;
  int lane = (int)(r1 & 63);
  size_t r2 = r1 >> 6;
  int ks = (int)(r2 % 12);
  size_t r3 = r2 / 12;
  int nt = (int)(r3 % 24);
  size_t r4 = r3 / 24;
  int isl = (int)(r4 & 3);
  int L = (int)(r4 >> 2);
  int cz = nt * 16 + (lane & 15);
  int gate = cz & 3;
  int jj = cz >> 2;
  int gcol = gate * 384 + isl * 96 + jj;
  int k2d = ks * 16 + (lane >> 4) * 4 + d;
  const float* src = Wh + ((size_t)L * 384 + 2 * k2d) * 1536 + gcol;
  f16x2 v;
  v[0] = (f16)src[0];
  v[1] = (f16)src[1536];
  whB[idx] = v;
}

// ---------------------------------------------------------------------------
// Standalone chunked xg GEMM (primes chunk 0 of each layer).
// ---------------------------------------------------------------------------
__global__ __launch_bounds__(256) void gemm_xg_kernel(
    const f16* __restrict__ act, const float* __restrict__ Bw,
    f16* __restrict__ C, int lo) {
  __shared__ f16x2 As2[8 * 136];
  __shared__ f16x2 Bs2[8 * 128];
  int tid = threadIdx.x;
  int n0 = blockIdx.x * 128;
  int m0 = blockIdx.y * 128;
  int am = tid >> 2;
  int ak = (tid & 3) * 4;
  int bk = tid >> 5;
  int bn = (tid & 31) * 4;
  int row0 = m0 + am, row1 = row0 + 64;
  const f16* Ap0 = act + ((size_t)(row0 / TC) * T_OUT + lo + row0 % TC) * HDIM + ak;
  const f16* Ap1 = act + ((size_t)(row1 / TC) * T_OUT + lo + row1 % TC) * HDIM + ak;
  const float* Bp = Bw + (size_t)(2 * bk) * GDIM + n0 + bn;
  f16x4 ra0 = *(const f16x4*)Ap0;
  f16x4 ra1 = *(const f16x4*)Ap1;
  float4 rb0 = *(const float4*)Bp;
  float4 rb1 = *(const float4*)(Bp + (size_t)GDIM);
  float acc[8][8];
#pragma unroll
  for (int i = 0; i < 8; ++i)
#pragma unroll
    for (int j = 0; j < 8; ++j) acc[i][j] = 0.f;
  int tx = tid & 15, ty = tid >> 4;
  for (int kt = 0; kt < 24; ++kt) {
    int ak2 = ak >> 1;
    As2[(ak2 + 0) * 136 + am] = (f16x2){ra0[0], ra0[1]};
    As2[(ak2 + 1) * 136 + am] = (f16x2){ra0[2], ra0[3]};
    As2[(ak2 + 0) * 136 + am + 64] = (f16x2){ra1[0], ra1[1]};
    As2[(ak2 + 1) * 136 + am + 64] = (f16x2){ra1[2], ra1[3]};
    Bs2[bk * 128 + bn + 0] = (f16x2){(f16)rb0.x, (f16)rb1.x};
    Bs2[bk * 128 + bn + 1] = (f16x2){(f16)rb0.y, (f16)rb1.y};
    Bs2[bk * 128 + bn + 2] = (f16x2){(f16)rb0.z, (f16)rb1.z};
    Bs2[bk * 128 + bn + 3] = (f16x2){(f16)rb0.w, (f16)rb1.w};
    __syncthreads();
    if (kt < 23) {
      Ap0 += 16; Ap1 += 16; Bp += (size_t)16 * GDIM;
      ra0 = *(const f16x4*)Ap0;
      ra1 = *(const f16x4*)Ap1;
      rb0 = *(const float4*)Bp;
      rb1 = *(const float4*)(Bp + (size_t)GDIM);
    }
#pragma unroll
    for (int k2 = 0; k2 < 8; ++k2) {
      f16x8 a0 = *(const f16x8*)&As2[k2 * 136 + ty * 4];
      f16x8 a1 = *(const f16x8*)&As2[k2 * 136 + 64 + ty * 4];
      f16x8 b0 = *(const f16x8*)&Bs2[k2 * 128 + tx * 4];
      f16x8 b1 = *(const f16x8*)&Bs2[k2 * 128 + 64 + tx * 4];
      f16x2 av[8], bv[8];
#pragma unroll
      for (int q = 0; q < 4; ++q) {
        av[q] = (f16x2){a0[2 * q], a0[2 * q + 1]};
        av[q + 4] = (f16x2){a1[2 * q], a1[2 * q + 1]};
        bv[q] = (f16x2){b0[2 * q], b0[2 * q + 1]};
        bv[q + 4] = (f16x2){b1[2 * q], b1[2 * q + 1]};
      }
#pragma unroll
      for (int i = 0; i < 8; ++i)
#pragma unroll
        for (int j = 0; j < 8; ++j) acc[i][j] = fdot2(av[i], bv[j], acc[i][j]);
    }
    __syncthreads();
  }
#pragma unroll
  for (int i = 0; i < 8; ++i) {
    int mi = (i < 4) ? (ty * 4 + i) : (64 + ty * 4 + i - 4);
    f16* Cp = C + (size_t)(m0 + mi) * GDIM + n0;
    f16x4 p0, p1;
    p0[0] = (f16)acc[i][0]; p0[1] = (f16)acc[i][1]; p0[2] = (f16)acc[i][2]; p0[3] = (f16)acc[i][3];
    p1[0] = (f16)acc[i][4]; p1[1] = (f16)acc[i][5]; p1[2] = (f16)acc[i][6]; p1[3] = (f16)acc[i][7];
    *(f16x4*)(Cp + tx * 4) = p0;
    *(f16x4*)(Cp + 64 + tx * 4) = p1;
  }
}

// ---------------------------------------------------------------------------
// FUSED kernel: 256 blocks x 768 threads.
//  blocks 0..63: systolic LSTM, 4-slice regroup: 16 groups (8 batches) x 4
//    column-slices (96 h-cols, 2 MFMA N-tiles/wave, 96 pinned weight VGPRs).
//    Peers per group: 3 (was 7); poll units: <=1 per thread (was 1-2).
//    M=16 tiles half-filled (rows 8-15 zero, outputs unused) - MFMA is cheap.
//    Exchange: round-5 tag-in-payload protocol, byte-identical mechanics.
//  blocks 64..255: GEMM for next chunk at lo_g; 3 sub-tiles/block.
// ---------------------------------------------------------------------------
#define HSTR 784   // padded h2s row stride in bytes (768 data + 16 pad)

union FusedSh {
  struct { char h2s[16 * HSTR]; unsigned pub[16 * 25]; } L;    // 12544+1600 B
  struct { f16x2 As2[3][8 * 136]; f16x2 Bs2[3][8 * 128]; } G;  // 25344 B
  char pad[25600];
};

__global__ __launch_bounds__(768, 1) void fused_kernel(
    const f16* __restrict__ xgc_rd, f16* __restrict__ xgc_wr,
    const f16* __restrict__ whB, const float* __restrict__ bias,
    f16* __restrict__ act, float* __restrict__ cst, const float* __restrict__ Wi,
    unsigned* __restrict__ xh,
    int lo_l, int lo_g, int reverse, int first, int do_gemm, int epoch) {
  __shared__ FusedSh sh;
  int tid = threadIdx.x;

  if (blockIdx.x < NLB) {
    // ================= systolic LSTM branch (MFMA, 4-slice) =================
    int wid = blockIdx.x;
    int g = wid & 15;            // group 0..15 (8 batches)
    int isl = wid >> 4;          // column slice 0..3 (96 h-cols)
    int b0 = g * 8;
    int w = tid >> 6;            // wave 0..11 -> N-tiles 2w, 2w+1
    int l = tid & 63;
    int lk = l >> 4;             // 0..3; batches live in lk<2 (row=lk*4+r)
    int qj = (l >> 2) & 3;
    int gate = l & 3;
    int jj0 = w * 8 + qj;        // tile 2w   col group
    int hcol0 = isl * 96 + jj0;  // tile 2w+1: +4
    int gcol0 = gate * 384 + hcol0;
    int bq = (lk & 1) * 4;       // batch quad base (lanes lk>=2 duplicate)

    // --- B-frag weights -> 96 VGPRs (2 tiles x 12 ks), loaded once, pinned ---
    f16x8 wreg[2][12];
    {
      const f16x8* wp = (const f16x8*)whB + (size_t)(isl * 24 + 2 * w) * 12 * 64 + l;
#pragma unroll
      for (int ks = 0; ks < 12; ++ks) {
        wreg[0][ks] = wp[(size_t)ks * 64];
        wreg[1][ks] = wp[(size_t)(12 + ks) * 64];
      }
#pragma unroll
      for (int ks = 0; ks < 12; ++ks) {
        asm volatile("" : "+v"(wreg[0][ks]));
        asm volatile("" : "+v"(wreg[1][ks]));
      }
    }
    float bias0 = bias[gcol0];
    float bias1 = bias[gcol0 + 4];

    float c0[4], c1[4];
    if (first) {
#pragma unroll
      for (int r = 0; r < 4; ++r) { c0[r] = 0.f; c1[r] = 0.f; }
      for (int i = tid; i < 784; i += 768)
        *(f16x8*)(sh.L.h2s + i * 16) = (f16x8){};
    } else {
      int tprev = reverse ? (lo_l + TC) : (lo_l - 1);
#pragma unroll
      for (int r = 0; r < 4; ++r) {
        c0[r] = cst[(size_t)(b0 + bq + r) * HDIM + hcol0];
        c1[r] = cst[(size_t)(b0 + bq + r) * HDIM + hcol0 + 4];
      }
      // rows 0..7 <- act(tprev); rows 8..15 <- 0
      int flat = tid * 4;
      int bt = flat / 384, cc0 = flat % 384;
      *(f16x4*)(sh.L.h2s + bt * HSTR + cc0 * 2) =
          *(const f16x4*)(act + ((size_t)(b0 + bt) * T_OUT + tprev) * HDIM + cc0);
      if (tid < 392) {
        int row = 8 + tid / 49, off = (tid % 49) * 16;
        *(f16x8*)(sh.L.h2s + row * HSTR + off) = (f16x8){};
      }
    }
    __syncthreads();

    const char* arow = sh.L.h2s + (l & 15) * HSTR + lk * 16;
    unsigned short* pubh = (unsigned short*)sh.L.pub;   // rows of 98 halves

    // xg preload for step 0 (2 cols x 4 batches)
    float xv0[4], xv1[4];
    {
      int tl0 = reverse ? (TC - 1) : 0;
      const f16* xb = xgc_rd + ((size_t)(b0 + bq) * TC + tl0) * GDIM + gcol0;
#pragma unroll
      for (int r = 0; r < 4; ++r) {
        xv0[r] = (float)xb[(size_t)r * TC * GDIM];
        xv1[r] = (float)xb[(size_t)r * TC * GDIM + 4];
      }
    }

    for (int s = 0; s < TC; ++s) {
      int t = reverse ? (lo_l + TC - 1 - s) : (lo_l + s);

      // --- z = h @ Wslice via MFMA: 2 N-tiles, shared A-frag ---
      f32x4 acc0 = {0.f, 0.f, 0.f, 0.f};
      f32x4 acc1 = {0.f, 0.f, 0.f, 0.f};
#pragma unroll
      for (int ks = 0; ks < 12; ++ks) {
        f16x8 a = *(const f16x8*)(arow + ks * 64);
        acc0 = __builtin_amdgcn_mfma_f32_16x16x32_f16(a, wreg[0][ks], acc0, 0, 0, 0);
        acc1 = __builtin_amdgcn_mfma_f32_16x16x32_f16(a, wreg[1][ks], acc1, 0, 0, 0);
      }

      // --- gates: quad butterfly, per tile ---
      f16 h0[4], h1[4];
#pragma unroll
      for (int r = 0; r < 4; ++r) {
        {
          float a = acc0[r] + xv0[r] + bias0;
          float b = __shfl_xor(a, 1);
          float cc = __shfl_xor(a, 2);
          float dd = __shfl_xor(b, 2);
          float zi = (gate == 0) ? a : (gate == 1) ? b : (gate == 2) ? cc : dd;
          float zf = (gate == 1) ? a : (gate == 0) ? b : (gate == 3) ? cc : dd;
          float zg = (gate == 2) ? a : (gate == 3) ? b : (gate == 0) ? cc : dd;
          float zo = (gate == 3) ? a : (gate == 2) ? b : (gate == 1) ? cc : dd;
          float ig = sigf(zi), fg = sigf(zf), gv = tanh_fast(zg), og = sigf(zo);
          c0[r] = fg * c0[r] + ig * gv;
          h0[r] = (f16)(og * tanh_fast(c0[r]));
        }
        {
          float a = acc1[r] + xv1[r] + bias1;
          float b = __shfl_xor(a, 1);
          float cc = __shfl_xor(a, 2);
          float dd = __shfl_xor(b, 2);
          float zi = (gate == 0) ? a : (gate == 1) ? b : (gate == 2) ? cc : dd;
          float zf = (gate == 1) ? a : (gate == 0) ? b : (gate == 3) ? cc : dd;
          float zg = (gate == 2) ? a : (gate == 3) ? b : (gate == 0) ? cc : dd;
          float zo = (gate == 3) ? a : (gate == 2) ? b : (gate == 1) ? cc : dd;
          float ig = sigf(zi), fg = sigf(zf), gv = tanh_fast(zg), og = sigf(zo);
          c1[r] = fg * c1[r] + ig * gv;
          h1[r] = (f16)(og * tanh_fast(c1[r]));
        }
      }

      if (s + 1 < TC) {
        unsigned tag = (unsigned)(epoch * TC + s + 1);
        unsigned* slotbase = xh + (size_t)(s & 1) * 128 * 256;

        // --- stage own h slice into LDS pub (8 rows x 96 cols, 98-half rows)
        if (gate == 0 && lk < 2) {
#pragma unroll
          for (int r = 0; r < 4; ++r) {
            pubh[(lk * 4 + r) * 98 + jj0] = __builtin_bit_cast(unsigned short, h0[r]);
            pubh[(lk * 4 + r) * 98 + jj0 + 4] = __builtin_bit_cast(unsigned short, h1[r]);
          }
        }
        __syncthreads();  // barrier A: pub staged (MFMA h2s reads also done)

        // --- publish: 128 threads x one 16B unit (3 data words + tag) ---
        if (tid < 128) {
          int bt = tid >> 4, u = tid & 15;
          const unsigned* pw = sh.L.pub + bt * 49 + u * 3;
          u32x4 dnew;
          dnew[0] = pw[0]; dnew[1] = pw[1]; dnew[2] = pw[2]; dnew[3] = tag;
          u32x4* dp = (u32x4*)(slotbase + (((size_t)(b0 + bt) * 64) + isl * 16 + u) * 4);
          asm volatile("global_store_dwordx4 %0, %1, off sc0 sc1"
                       :: "v"(dp), "v"(dnew) : "memory");
        }

        // --- hidden under flight: act store + next-step xg prefetch ---
        if (gate == 0 && lk < 2) {
#pragma unroll
          for (int r = 0; r < 4; ++r) {
            act[((size_t)(b0 + lk * 4 + r) * T_OUT + t) * HDIM + hcol0] = h0[r];
            act[((size_t)(b0 + lk * 4 + r) * T_OUT + t) * HDIM + hcol0 + 4] = h1[r];
          }
        }
        {
          int tl_n = reverse ? (TC - 2 - s) : (s + 1);
          const f16* xb = xgc_rd + ((size_t)(b0 + bq) * TC + tl_n) * GDIM + gcol0;
#pragma unroll
          for (int r = 0; r < 4; ++r) {
            xv0[r] = (float)xb[(size_t)r * TC * GDIM];
            xv1[r] = (float)xb[(size_t)r * TC * GDIM + 4];
          }
        }

        // --- poll-gather: 512 units (8 batches x 64), <=1 per thread ---
        if (tid < 512) {
          int bt = tid >> 6, rem = tid & 63;
          int isl_src = rem >> 4, u = rem & 15;
          unsigned* dst = (unsigned*)(sh.L.h2s + bt * HSTR + isl_src * 192 + u * 12);
          if (isl_src == isl) {
            const unsigned* pw = sh.L.pub + bt * 49 + u * 3;
            dst[0] = pw[0]; dst[1] = pw[1]; dst[2] = pw[2];
          } else {
            const u32x4* up = (const u32x4*)(slotbase + (((size_t)(b0 + bt) * 64) + rem) * 4);
            u32x4 v;
            while (true) {
              asm volatile("global_load_dwordx4 %0, %1, off sc0 sc1\n\ts_waitcnt vmcnt(0)"
                           : "=v"(v) : "v"(up) : "memory");
              if (v[3] >= tag) break;
              __builtin_amdgcn_s_sleep(1);
            }
            dst[0] = v[0]; dst[1] = v[1]; dst[2] = v[2];
          }
        }
        __syncthreads();  // barrier B: h2s complete for next step
      } else {
        if (gate == 0 && lk < 2) {
#pragma unroll
          for (int r = 0; r < 4; ++r) {
            act[((size_t)(b0 + lk * 4 + r) * T_OUT + t) * HDIM + hcol0] = h0[r];
            act[((size_t)(b0 + lk * 4 + r) * T_OUT + t) * HDIM + hcol0 + 4] = h1[r];
          }
        }
      }
    }
    if (gate == 0 && lk < 2) {
#pragma unroll
      for (int r = 0; r < 4; ++r) {
        cst[(size_t)(b0 + lk * 4 + r) * HDIM + hcol0] = c0[r];
        cst[(size_t)(b0 + lk * 4 + r) * HDIM + hcol0 + 4] = c1[r];
      }
    }
  } else {
    // ================= GEMM worker branch =================
    if (!do_gemm) return;
    int wid = blockIdx.x - NLB;       // 0..191
    int sub = tid >> 8;               // 0..2 (wave-uniform)
    int stid = tid & 255;
    int tileid = wid + 192 * sub;     // 0..575
    bool valid = (tileid < NTILES);
    int tclamp = valid ? tileid : 0;
    int n0 = (tclamp % 12) * 128;
    int m0 = (tclamp / 12) * 128;
    f16x2* As2 = &sh.G.As2[sub][0];
    f16x2* Bs2 = &sh.G.Bs2[sub][0];
    int am = stid >> 2;
    int ak = (stid & 3) * 4;
    int bk = stid >> 5;
    int bn = (stid & 31) * 4;
    int row0 = m0 + am, row1 = row0 + 64;
    const f16* Ap0 = act + ((size_t)(row0 / TC) * T_OUT + lo_g + row0 % TC) * HDIM + ak;
    const f16* Ap1 = act + ((size_t)(row1 / TC) * T_OUT + lo_g + row1 % TC) * HDIM + ak;
    const float* Bp = Wi + (size_t)(2 * bk) * GDIM + n0 + bn;
    f16x4 ra0 = {}, ra1 = {};
    float4 rb0 = {}, rb1 = {};
    if (valid) {
      ra0 = *(const f16x4*)Ap0;
      ra1 = *(const f16x4*)Ap1;
      rb0 = *(const float4*)Bp;
      rb1 = *(const float4*)(Bp + (size_t)GDIM);
    }
    float acc[8][8];
#pragma unroll
    for (int i = 0; i < 8; ++i)
#pragma unroll
      for (int j = 0; j < 8; ++j) acc[i][j] = 0.f;
    int tx = stid & 15, ty = stid >> 4;
    for (int kt = 0; kt < 24; ++kt) {
      if (valid) {
        int ak2 = ak >> 1;
        As2[(ak2 + 0) * 136 + am] = (f16x2){ra0[0], ra0[1]};
        As2[(ak2 + 1) * 136 + am] = (f16x2){ra0[2], ra0[3]};
        As2[(ak2 + 0) * 136 + am + 64] = (f16x2){ra1[0], ra1[1]};
        As2[(ak2 + 1) * 136 + am + 64] = (f16x2){ra1[2], ra1[3]};
        Bs2[bk * 128 + bn + 0] = (f16x2){(f16)rb0.x, (f16)rb1.x};
        Bs2[bk * 128 + bn + 1] = (f16x2){(f16)rb0.y, (f16)rb1.y};
        Bs2[bk * 128 + bn + 2] = (f16x2){(f16)rb0.z, (f16)rb1.z};
        Bs2[bk * 128 + bn + 3] = (f16x2){(f16)rb0.w, (f16)rb1.w};
      }
      __syncthreads();
      if (valid) {
        if (kt < 23) {
          Ap0 += 16; Ap1 += 16; Bp += (size_t)16 * GDIM;
          ra0 = *(const f16x4*)Ap0;
          ra1 = *(const f16x4*)Ap1;
          rb0 = *(const float4*)Bp;
          rb1 = *(const float4*)(Bp + (size_t)GDIM);
        }
#pragma unroll
        for (int k2i = 0; k2i < 8; ++k2i) {
          f16x8 a0 = *(const f16x8*)&As2[k2i * 136 + ty * 4];
          f16x8 a1 = *(const f16x8*)&As2[k2i * 136 + 64 + ty * 4];
          f16x8 b0 = *(const f16x8*)&Bs2[k2i * 128 + tx * 4];
          f16x8 b1 = *(const f16x8*)&Bs2[k2i * 128 + 64 + tx * 4];
          f16x2 av[8], bv[8];
#pragma unroll
          for (int qq = 0; qq < 4; ++qq) {
            av[qq] = (f16x2){a0[2 * qq], a0[2 * qq + 1]};
            av[qq + 4] = (f16x2){a1[2 * qq], a1[2 * qq + 1]};
            bv[qq] = (f16x2){b0[2 * qq], b0[2 * qq + 1]};
            bv[qq + 4] = (f16x2){b1[2 * qq], b1[2 * qq + 1]};
          }
#pragma unroll
          for (int i = 0; i < 8; ++i)
#pragma unroll
            for (int j = 0; j < 8; ++j) acc[i][j] = fdot2(av[i], bv[j], acc[i][j]);
        }
      }
      __syncthreads();
    }
    if (valid) {
#pragma unroll
      for (int i = 0; i < 8; ++i) {
        int mi = (i < 4) ? (ty * 4 + i) : (64 + ty * 4 + i - 4);
        f16* Cp = xgc_wr + (size_t)(m0 + mi) * GDIM + n0;
        f16x4 p0, p1;
        p0[0] = (f16)acc[i][0]; p0[1] = (f16)acc[i][1]; p0[2] = (f16)acc[i][2]; p0[3] = (f16)acc[i][3];
        p1[0] = (f16)acc[i][4]; p1[1] = (f16)acc[i][5]; p1[2] = (f16)acc[i][6]; p1[3] = (f16)acc[i][7];
        *(f16x4*)(Cp + tx * 4) = p0;
        *(f16x4*)(Cp + 64 + tx * 4) = p1;
      }
    }
  }
}

// ---------------------------------------------------------------------------
// dense: out(204800,5) = h(204800,384 fp16) @ W(384,5) + b  (fp32 out)
// ---------------------------------------------------------------------------
__global__ __launch_bounds__(256) void dense_kernel(
    const f16* __restrict__ h, const float* __restrict__ dw,
    const float* __restrict__ db, float* __restrict__ out) {
  __shared__ float ws_[1920];
  __shared__ float bs[5];
  int tid = threadIdx.x;
  for (int i = tid; i < 1920; i += 256) ws_[i] = dw[i];
  if (tid < 5) bs[tid] = db[tid];
  __syncthreads();
  size_t flat = (size_t)blockIdx.x * 256 + tid;
  const f16* hp = h + flat * HDIM;
  float acc[5];
#pragma unroll
  for (int o = 0; o < 5; ++o) acc[o] = bs[o];
  for (int d = 0; d < HDIM; d += 4) {
    f16x4 hv = *(const f16x4*)(hp + d);
#pragma unroll
    for (int o = 0; o < 5; ++o) {
      acc[o] = fmaf((float)hv[0], ws_[(d + 0) * 5 + o], acc[o]);
      acc[o] = fmaf((float)hv[1], ws_[(d + 1) * 5 + o], acc[o]);
      acc[o] = fmaf((float)hv[2], ws_[(d + 2) * 5 + o], acc[o]);
      acc[o] = fmaf((float)hv[3], ws_[(d + 3) * 5 + o], acc[o]);
    }
  }
  float* op = out + flat * 5;
#pragma unroll
  for (int o = 0; o < 5; ++o) op[o] = acc[o];
}

// ---------------------------------------------------------------------------
extern "C" void kernel_launch(void* const* d_in, const int* in_sizes, int n_in,
                              void* d_out, int out_size, void* d_ws, size_t ws_size,
                              hipStream_t stream) {
  const float* x  = (const float*)d_in[0];
  const float* w1 = (const float*)d_in[1];
  const float* b1 = (const float*)d_in[2];
  const float* w2 = (const float*)d_in[3];
  const float* b2 = (const float*)d_in[4];
  const float* w3 = (const float*)d_in[5];
  const float* b3 = (const float*)d_in[6];
  const float* Wi = (const float*)d_in[7];
  const float* Wh = (const float*)d_in[8];
  const float* lb = (const float*)d_in[9];
  const float* dw = (const float*)d_in[10];
  const float* db = (const float*)d_in[11];
  float* out = (float*)d_out;
  char* ws = (char*)d_ws;

  // ws (~195.4 MB <= proven 197): act | xgcA | xgcB | whB | cst | xh | w3t
  const size_t ACT_BYTES = (size_t)B_SZ * T_OUT * HDIM * 2;   // 157.3 MB
  const size_t XGC_BYTES = (size_t)B_SZ * TC * GDIM * 2;      // 15.7 MB each
  const size_t WHB_BYTES = (size_t)5 * 4 * 24 * 12 * 64 * 16; // 5.9 MB
  const size_t CST_BYTES = (size_t)B_SZ * HDIM * 4;           // 196.6 KB
  const size_t XH_BYTES  = (size_t)2 * 128 * 64 * 16;         // 256 KB
  const size_t W3T_BYTES = (size_t)384 * 320 * 2;             // 240 KB
  f16*      act  = (f16*)ws;
  f16*      xgcA = (f16*)(ws + ACT_BYTES);
  f16*      xgcB = (f16*)(ws + ACT_BYTES + XGC_BYTES);
  f16*      whB  = (f16*)(ws + ACT_BYTES + 2 * XGC_BYTES);
  float*    cst  = (float*)(ws + ACT_BYTES + 2 * XGC_BYTES + WHB_BYTES);
  unsigned* xh   = (unsigned*)(ws + ACT_BYTES + 2 * XGC_BYTES + WHB_BYTES + CST_BYTES);
  f16*      w3t  = (f16*)(ws + ACT_BYTES + 2 * XGC_BYTES + WHB_BYTES + CST_BYTES + XH_BYTES);
  f16* y2 = xgcA;  // alias: consumed before xgc/whB are written

  hipMemsetAsync(xh, 0, XH_BYTES, stream);  // zero tags (monotonic from 1)

  hipLaunchKernelGGL(conv12_kernel, dim3(B_SZ * T_IN / 256), dim3(256), 0, stream,
                     x, w1, b1, w2, b2, y2);
  hipLaunchKernelGGL(w3cvt_kernel, dim3(384 * 320 / 256), dim3(256), 0, stream,
                     w3, w3t);
  hipLaunchKernelGGL(conv3_kernel, dim3(T_OUT / C3M, B_SZ), dim3(384), 0, stream,
                     y2, w3t, b3, act);
  hipLaunchKernelGGL(whcvt_kernel, dim3((unsigned)(WHB_BYTES / 4 / 256)), dim3(256), 0, stream,
                     Wh, (f16x2*)whB);

  for (int l = 0; l < 5; ++l) {
    int rev = (l % 2 == 0) ? 1 : 0;
    const float* wi_p = Wi + (size_t)l * HDIM * GDIM;
    const f16* wh_p = whB + (size_t)l * 4 * 24 * 12 * 64 * 8;
    const float* lb_p = lb + (size_t)l * GDIM;
    int lo0 = rev ? (T_OUT - TC) : 0;
    hipLaunchKernelGGL(gemm_xg_kernel, dim3(GDIM / 128, (B_SZ * TC) / 128), dim3(256), 0, stream,
                       act, wi_p, xgcA, lo0);
    for (int ci = 0; ci < NCHUNK; ++ci) {
      int lo_l = rev ? (T_OUT - (ci + 1) * TC) : (ci * TC);
      int do_gemm = (ci + 1 < NCHUNK) ? 1 : 0;
      int lo_g = do_gemm ? (rev ? (T_OUT - (ci + 2) * TC) : ((ci + 1) * TC)) : 0;
      f16* rd = (ci % 2 == 0) ? xgcA : xgcB;
      f16* wr = (ci % 2 == 0) ? xgcB : xgcA;
      int epoch = l * NCHUNK + ci;
      hipLaunchKernelGGL(fused_kernel, dim3(256), dim3(768), 0, stream,
                         rd, wr, wh_p, lb_p, act, cst, wi_p, xh,
                         lo_l, lo_g, rev, (ci == 0) ? 1 : 0, do_gemm, epoch);
    }
  }
  hipLaunchKernelGGL(dense_kernel, dim3((B_SZ * T_OUT) / 256), dim3(256), 0, stream,
                     act, dw, db, out);
}

// Round 9
// 29119.373 us; speedup vs baseline: 1.2808x; 1.2808x over previous
//
#include <hip/hip_runtime.h>
#include <math.h>

#define B_SZ 128
#define T_IN 8000
#define T_OUT 1600
#define HDIM 384
#define GDIM 1536   // 4*H
#define TC 40       // time chunk
#define NCHUNK (T_OUT / TC)   // 40
#define NTILES (12 * (B_SZ * TC / 128))   // 480 gemm tiles per chunk
#define NLB 64            // LSTM blocks: 8 groups x 8 column-slices

typedef _Float16 f16;
typedef __attribute__((ext_vector_type(2))) _Float16 f16x2;
typedef __attribute__((ext_vector_type(4))) _Float16 f16x4;
typedef __attribute__((ext_vector_type(8))) _Float16 f16x8;
typedef __attribute__((ext_vector_type(4))) float f32x4;
typedef __attribute__((ext_vector_type(4))) unsigned int u32x4;
typedef __attribute__((ext_vector_type(2))) unsigned int u32x2;

__device__ inline float fdot2(f16x2 a, f16x2 b, float c) {
#if __has_builtin(__builtin_amdgcn_fdot2)
  return __builtin_amdgcn_fdot2(a, b, c, false);
#else
  return fmaf((float)a[0], (float)b[0], fmaf((float)a[1], (float)b[1], c));
#endif
}

__device__ inline float rcp_fast(float x) {
#if __has_builtin(__builtin_amdgcn_rcpf)
  return __builtin_amdgcn_rcpf(x);
#else
  return 1.f / x;
#endif
}
__device__ inline float sigf(float z) { return rcp_fast(1.f + __expf(-z)); }
__device__ inline float tanh_fast(float z) {
  z = fminf(fmaxf(z, -15.f), 15.f);
  float e = __expf(2.f * z);
  return (e - 1.f) * rcp_fast(e + 1.f);
}
__device__ inline float u16f(unsigned u) {
  unsigned short us = (unsigned short)u;
  return (float)__builtin_bit_cast(_Float16, us);
}

// ---------------------------------------------------------------------------
// conv1 (5,1,4) + silu + conv2 (5,4,16) + silu, fused. One thread per (b,t).
// ---------------------------------------------------------------------------
__global__ __launch_bounds__(256) void conv12_kernel(
    const float* __restrict__ x, const float* __restrict__ w1, const float* __restrict__ b1,
    const float* __restrict__ w2, const float* __restrict__ b2, f16* __restrict__ y2) {
  __shared__ float sw1[20], sb1[4], sw2[320], sb2[16];
  int tid = threadIdx.x;
  if (tid < 20) sw1[tid] = w1[tid];
  if (tid < 4)  sb1[tid] = b1[tid];
  if (tid < 16) sb2[tid] = b2[tid];
  for (int i = tid; i < 320; i += 256) sw2[i] = w2[i];
  __syncthreads();
  int flat = blockIdx.x * 256 + tid;
  int b = flat / T_IN, t = flat % T_IN;
  const float* xb = x + (size_t)b * T_IN;
  float xv[9];
#pragma unroll
  for (int d = 0; d < 9; ++d) {
    int tt = t + d - 4;
    xv[d] = (tt >= 0 && tt < T_IN) ? xb[tt] : 0.f;
  }
  float y1[5][4];
#pragma unroll
  for (int u = 0; u < 5; ++u) {
    int tau = t + u - 2;
    bool valid = (tau >= 0 && tau < T_IN);
#pragma unroll
    for (int co = 0; co < 4; ++co) {
      float a = sb1[co];
#pragma unroll
      for (int k = 0; k < 5; ++k) a = fmaf(xv[u + k], sw1[k * 4 + co], a);
      y1[u][co] = valid ? (a / (1.f + expf(-a))) : 0.f;
    }
  }
  f16x8 o0, o1;
#pragma unroll
  for (int co = 0; co < 16; ++co) {
    float a = sb2[co];
#pragma unroll
    for (int u = 0; u < 5; ++u)
#pragma unroll
      for (int ci = 0; ci < 4; ++ci)
        a = fmaf(y1[u][ci], sw2[(u * 4 + ci) * 16 + co], a);
    float sv = a / (1.f + expf(-a));
    if (co < 8) o0[co] = (f16)sv; else o1[co - 8] = (f16)sv;
  }
  f16x8* dst = (f16x8*)(y2 + (size_t)flat * 16);
  dst[0] = o0;
  dst[1] = o1;
}

// ---------------------------------------------------------------------------
// w3 -> transposed f16 [c][k] (K padded 304->320 with zeros).
// ---------------------------------------------------------------------------
__global__ __launch_bounds__(256) void w3cvt_kernel(
    const float* __restrict__ w3, f16* __restrict__ w3t) {
  int idx = blockIdx.x * 256 + threadIdx.x;   // 384*320 = 122880
  int c = idx / 320, k = idx - c * 320;
  w3t[idx] = (k < 304) ? (f16)w3[(size_t)k * 384 + c] : (f16)0.f;
}

// ---------------------------------------------------------------------------
// conv3 via MFMA (verified round 6).
// ---------------------------------------------------------------------------
#define C3M 32
#define C3K 320
#define INSP 24
#define BSTP 40

__global__ __launch_bounds__(384) void conv3_kernel(
    const f16* __restrict__ y2, const f16* __restrict__ w3t,
    const float* __restrict__ b3, f16* __restrict__ act) {
  __shared__ f16 in_s[176 * INSP];
  __shared__ f16 bs_t[384 * BSTP];
  int tid = threadIdx.x;
  int b = blockIdx.y;
  int t0 = blockIdx.x * C3M;
  int base_t = t0 * 5 - 7;
  for (int j = tid; j < 352; j += 384) {
    int tau = j >> 1, ci0 = (j & 1) * 8;
    int tt = base_t + tau;
    f16x8 v = {};
    if (tt >= 0 && tt < T_IN)
      v = *(const f16x8*)(y2 + ((size_t)b * T_IN + tt) * 16 + ci0);
    *(f16x8*)&in_s[tau * INSP + ci0] = v;
  }
  int wv = tid >> 6;
  int l = tid & 63;
  int lm = l & 15;
  int lk = l >> 4;
  f32x4 acc[2][4];
#pragma unroll
  for (int mt = 0; mt < 2; ++mt)
#pragma unroll
    for (int q = 0; q < 4; ++q) acc[mt][q] = (f32x4){0.f, 0.f, 0.f, 0.f};
  for (int ks = 0; ks < 10; ++ks) {
    __syncthreads();
    for (int u = tid; u < 1536; u += 384) {
      int c = u >> 2, k8 = u & 3;
      *(f16x8*)&bs_t[c * BSTP + k8 * 8] =
          *(const f16x8*)(w3t + (size_t)c * C3K + ks * 32 + k8 * 8);
    }
    __syncthreads();
    int kg = ks * 32 + lk * 8;
    int kk = kg >> 4, ci = kg & 15;
    f16x8 a0 = *(const f16x8*)&in_s[(lm * 5 + kk) * INSP + ci];
    f16x8 a1 = *(const f16x8*)&in_s[((lm + 16) * 5 + kk) * INSP + ci];
#pragma unroll
    for (int q = 0; q < 4; ++q) {
      f16x8 bf = *(const f16x8*)&bs_t[((wv * 4 + q) * 16 + lm) * BSTP + lk * 8];
      acc[0][q] = __builtin_amdgcn_mfma_f32_16x16x32_f16(a0, bf, acc[0][q], 0, 0, 0);
      acc[1][q] = __builtin_amdgcn_mfma_f32_16x16x32_f16(a1, bf, acc[1][q], 0, 0, 0);
    }
  }
#pragma unroll
  for (int mt = 0; mt < 2; ++mt)
#pragma unroll
    for (int q = 0; q < 4; ++q) {
      int n = (wv * 4 + q) * 16 + lm;
      float bv = b3[n];
#pragma unroll
      for (int r = 0; r < 4; ++r) {
        int m = mt * 16 + lk * 4 + r;
        float a = acc[mt][q][r] + bv;
        a = a / (1.f + expf(-a));
        act[((size_t)b * T_OUT + t0 + m) * HDIM + n] = (f16)a;
      }
    }
}

// ---------------------------------------------------------------------------
// Wh -> MFMA B-fragment repack (8-slice layout, verified round 3).
// ---------------------------------------------------------------------------
__global__ __launch_bounds__(256) void whcvt_kernel(
    const float* __restrict__ Wh, f16x2* __restrict__ whB) {
  size_t idx = (size_t)blockIdx.x * 256 + threadIdx.x;
  int d = (int)(idx & 3);
  size_t r1 = idx >> 2;
  int lane = (int)(r1 & 63);
  size_t r2 = r1 >> 6;
  int ks = (int)(r2 % 12);
  size_t r3 = r2 / 12;
  int nt = (int)(r3 % 12);
  size_t r4 = r3 / 12;
  int isl = (int)(r4 & 7);
  int L = (int)(r4 >> 3);
  int cz = nt * 16 + (lane & 15);
  int gate = cz & 3;
  int jj = cz >> 2;
  int gcol = gate * 384 + isl * 48 + jj;
  int k2d = ks * 16 + (lane >> 4) * 4 + d;
  const float* src = Wh + ((size_t)L * 384 + 2 * k2d) * 1536 + gcol;
  f16x2 v;
  v[0] = (f16)src[0];
  v[1] = (f16)src[1536];
  whB[idx] = v;
}

// ---------------------------------------------------------------------------
// PERSISTENT per-layer fused kernel: 256 blocks x 768 threads, ONE launch
// covers all 40 chunks of a layer.
//  blocks 0..63: systolic LSTM (round-7 dataflow + tag-in-payload exchange,
//    byte-identical protocol). Weights/c/h2s stay resident across chunks.
//    Chunk boundaries exchange h at s=TC-1 too (next chunk needs it).
//    Per chunk: wait g_ctr >= 192*(ci+1); at end: l_ctr += 1.
//    xg reads via sc0 sc1 asm (cross-XCD, written in-kernel by GEMM).
//  blocks 64..255: GEMM pass ci=0..39 (includes the old priming pass).
//    Pass ci: wait l_ctr >= 64*(ci-1) (buffer free, ci>=2); read act window
//    W(ci) (previous-layer data, written before launch -> plain loads);
//    write xg buf[ci&1] via sc0 sc1 asm; vmcnt(0)+barrier; g_ctr += 1.
//  Ordering DAG: LSTM ci <- GEMM ci <- LSTM ci-2. No cycles; all blocks
//  resident (relied on since round 2).
// ---------------------------------------------------------------------------
#define HSTR 784   // padded h2s row stride in bytes (768 data + 16 pad)

union FusedSh {
  struct { char h2s[16 * HSTR]; unsigned pub[16 * 25]; } L;    // 12544+1600 B
  struct { f16x2 As2[3][8 * 136]; f16x2 Bs2[3][8 * 128]; } G;  // 25344 B
  char pad[25600];
};

__global__ __launch_bounds__(768, 1) void fused_layer_kernel(
    f16* __restrict__ xgA, f16* __restrict__ xgB,
    const f16* __restrict__ whB, const float* __restrict__ bias,
    f16* __restrict__ act, const float* __restrict__ Wi,
    unsigned* __restrict__ xh, unsigned* __restrict__ ctr2,
    int rev, int gbase) {
  __shared__ FusedSh sh;
  int tid = threadIdx.x;

  if (blockIdx.x < NLB) {
    // ================= systolic LSTM branch =================
    int wid = blockIdx.x;
    int g = wid & 7;             // group 0..7 (16 batches)
    int isl = wid >> 3;          // column slice 0..7 (48 h-cols)
    int b0 = g * 16;
    int nt = tid >> 6;           // wave id == N-tile 0..11
    int ln = tid & 63;
    int bg = ln >> 4;            // batches bg*4..bg*4+3
    int qj = (ln >> 2) & 3;
    int gate = ln & 3;
    int jj = nt * 4 + qj;
    int hcol = isl * 48 + jj;
    int gcol = gate * 384 + isl * 48 + jj;

    // B-frag weights -> 48 VGPRs, loaded ONCE PER LAYER, pinned.
    f16x8 wreg[12];
    {
      const f16x8* wp = (const f16x8*)whB + (size_t)(isl * 12 + nt) * 12 * 64 + ln;
#pragma unroll
      for (int ks = 0; ks < 12; ++ks) wreg[ks] = wp[(size_t)ks * 64];
#pragma unroll
      for (int ks = 0; ks < 12; ++ks) asm volatile("" : "+v"(wreg[ks]));
    }
    float bias_own = bias[gcol];

    float c_reg[4];
#pragma unroll
    for (int r = 0; r < 4; ++r) c_reg[r] = 0.f;
    for (int i = tid; i < 16 * HSTR / 16; i += 768)
      *(f16x8*)(sh.L.h2s + i * 16) = (f16x8){};
    __syncthreads();

    const char* arow = sh.L.h2s + (ln & 15) * HSTR + (ln >> 4) * 16;
    unsigned short* pubh = (unsigned short*)sh.L.pub;
    int k2 = (tid % 3 == 0) ? (768 + tid / 3) : -1;

    for (int ci = 0; ci < NCHUNK; ++ci) {
      int gci = gbase + ci;
      if (tid == 0) {
        unsigned tgt = 192u * (unsigned)(ci + 1);
        while (__hip_atomic_load(&ctr2[1], __ATOMIC_RELAXED, __HIP_MEMORY_SCOPE_AGENT) < tgt)
          __builtin_amdgcn_s_sleep(2);
      }
      __syncthreads();
      const f16* xgc_rd = (ci & 1) ? xgB : xgA;
      int lo_l = rev ? (T_OUT - (ci + 1) * TC) : (ci * TC);

      // chunk-start xg load (step 0), sc0 sc1 (written in-kernel by GEMM)
      unsigned xr[4];
      {
        int tl0 = rev ? (TC - 1) : 0;
        const f16* xb = xgc_rd + ((size_t)(b0 + bg * 4) * TC + tl0) * GDIM + gcol;
#pragma unroll
        for (int r = 0; r < 4; ++r)
          asm volatile("global_load_ushort %0, %1, off sc0 sc1"
                       : "=v"(xr[r]) : "v"(xb + (size_t)r * TC * GDIM) : "memory");
        asm volatile("s_waitcnt vmcnt(0)" ::: "memory");
        __builtin_amdgcn_sched_barrier(0);
      }

      for (int s = 0; s < TC; ++s) {
        int t = rev ? (lo_l + TC - 1 - s) : (lo_l + s);

        // z = h @ Wslice via MFMA
        f32x4 acc = {0.f, 0.f, 0.f, 0.f};
#pragma unroll
        for (int ks = 0; ks < 12; ++ks) {
          f16x8 a = *(const f16x8*)(arow + ks * 64);
          acc = __builtin_amdgcn_mfma_f32_16x16x32_f16(a, wreg[ks], acc, 0, 0, 0);
        }

        // gates: quad butterfly
        f16 h16[4];
#pragma unroll
        for (int r = 0; r < 4; ++r) {
          float a = acc[r] + u16f(xr[r]) + bias_own;
          float b = __shfl_xor(a, 1);
          float cc = __shfl_xor(a, 2);
          float dd = __shfl_xor(b, 2);
          float zi = (gate == 0) ? a : (gate == 1) ? b : (gate == 2) ? cc : dd;
          float zf = (gate == 1) ? a : (gate == 0) ? b : (gate == 3) ? cc : dd;
          float zg = (gate == 2) ? a : (gate == 3) ? b : (gate == 0) ? cc : dd;
          float zo = (gate == 3) ? a : (gate == 2) ? b : (gate == 1) ? cc : dd;
          float ig = sigf(zi), fg = sigf(zf), gv = tanh_fast(zg), og = sigf(zo);
          c_reg[r] = fg * c_reg[r] + ig * gv;
          h16[r] = (f16)(og * tanh_fast(c_reg[r]));
        }

        bool exch = (s + 1 < TC) || (ci + 1 < NCHUNK);
        if (exch) {
          unsigned tag = (unsigned)(gci * TC + s + 1);
          unsigned* slotbase = xh + (size_t)(s & 1) * 128 * 256;

          if (gate == 0) {
            int lcol = nt * 4 + qj;
#pragma unroll
            for (int r = 0; r < 4; ++r)
              pubh[(bg * 4 + r) * 50 + lcol] = __builtin_bit_cast(unsigned short, h16[r]);
          }
          __syncthreads();  // barrier A

          if (tid < 128) {
            int bt = tid >> 3, u = tid & 7;
            const unsigned* pw = sh.L.pub + bt * 25 + u * 3;
            u32x4 dnew;
            dnew[0] = pw[0]; dnew[1] = pw[1]; dnew[2] = pw[2]; dnew[3] = tag;
            u32x4* dp = (u32x4*)(slotbase + (((size_t)(b0 + bt) * 64) + isl * 8 + u) * 4);
            asm volatile("global_store_dwordx4 %0, %1, off sc0 sc1"
                         :: "v"(dp), "v"(dnew) : "memory");
          }

          if (gate == 0) {
#pragma unroll
            for (int r = 0; r < 4; ++r)
              act[((size_t)(b0 + bg * 4 + r) * T_OUT + t) * HDIM + hcol] = h16[r];
          }
          if (s + 1 < TC) {
            int tl_n = rev ? (TC - 2 - s) : (s + 1);
            const f16* xb = xgc_rd + ((size_t)(b0 + bg * 4) * TC + tl_n) * GDIM + gcol;
#pragma unroll
            for (int r = 0; r < 4; ++r)
              asm volatile("global_load_ushort %0, %1, off sc0 sc1"
                           : "=v"(xr[r]) : "v"(xb + (size_t)r * TC * GDIM) : "memory");
          }

          // poll-gather (round-7 verbatim)
          const u32x4* upA = nullptr; const u32x4* upB = nullptr;
          unsigned* dstA = nullptr; unsigned* dstB = nullptr;
#pragma unroll
          for (int uu = 0; uu < 2; ++uu) {
            int k = (uu == 0) ? tid : k2;
            if (uu == 1 && k < 0) break;
            int bt = k >> 6, rem = k & 63;
            int isl_src = rem >> 3, u = rem & 7;
            unsigned* dst = (unsigned*)(sh.L.h2s + bt * HSTR + isl_src * 96 + u * 12);
            if (isl_src == isl) {
              const unsigned* pw = sh.L.pub + bt * 25 + u * 3;
              dst[0] = pw[0]; dst[1] = pw[1]; dst[2] = pw[2];
            } else {
              const u32x4* up = (const u32x4*)(slotbase + (((size_t)(b0 + bt) * 64) + rem) * 4);
              if (!upA) { upA = up; dstA = dst; } else { upB = up; dstB = dst; }
            }
          }
          if (upA && !upB) {
            u32x4 v;
            while (true) {
              asm volatile("global_load_dwordx4 %0, %1, off sc0 sc1\n\ts_waitcnt vmcnt(0)"
                           : "=v"(v) : "v"(upA) : "memory");
              if (v[3] >= tag) break;
              __builtin_amdgcn_s_sleep(1);
            }
            dstA[0] = v[0]; dstA[1] = v[1]; dstA[2] = v[2];
          } else if (upA && upB) {
            u32x4 v0, v1;
            while (true) {
              asm volatile("global_load_dwordx4 %0, %2, off sc0 sc1\n\t"
                           "global_load_dwordx4 %1, %3, off sc0 sc1\n\t"
                           "s_waitcnt vmcnt(0)"
                           : "=&v"(v0), "=&v"(v1) : "v"(upA), "v"(upB) : "memory");
              if (v0[3] >= tag && v1[3] >= tag) break;
              __builtin_amdgcn_s_sleep(1);
            }
            dstA[0] = v0[0]; dstA[1] = v0[1]; dstA[2] = v0[2];
            dstB[0] = v1[0]; dstB[1] = v1[1]; dstB[2] = v1[2];
          }
          asm volatile("s_waitcnt vmcnt(0)" ::: "memory");
          __builtin_amdgcn_sched_barrier(0);
          __syncthreads();  // barrier B
        } else {
          if (gate == 0) {
#pragma unroll
            for (int r = 0; r < 4; ++r)
              act[((size_t)(b0 + bg * 4 + r) * T_OUT + t) * HDIM + hcol] = h16[r];
          }
        }
      }
      if (tid == 0)
        __hip_atomic_fetch_add(&ctr2[0], 1u, __ATOMIC_RELAXED, __HIP_MEMORY_SCOPE_AGENT);
    }
  } else {
    // ================= persistent GEMM worker branch =================
    int wid = blockIdx.x - NLB;       // 0..191
    int sub = tid >> 8;               // 0..2 (wave-uniform)
    int stid = tid & 255;
    int tileid = wid + 192 * sub;     // 0..575
    bool valid = (tileid < NTILES);
    int tclamp = valid ? tileid : 0;
    int n0 = (tclamp % 12) * 128;
    int m0 = (tclamp / 12) * 128;
    f16x2* As2 = &sh.G.As2[sub][0];
    f16x2* Bs2 = &sh.G.Bs2[sub][0];
    int am = stid >> 2;
    int ak = (stid & 3) * 4;
    int bk = stid >> 5;
    int bn = (stid & 31) * 4;
    int tx = stid & 15, ty = stid >> 4;
    int row0 = m0 + am, row1 = row0 + 64;

    for (int ci = 0; ci < NCHUNK; ++ci) {
      if (ci >= 2 && tid == 0) {
        unsigned tgt = 64u * (unsigned)(ci - 1);
        while (__hip_atomic_load(&ctr2[0], __ATOMIC_RELAXED, __HIP_MEMORY_SCOPE_AGENT) < tgt)
          __builtin_amdgcn_s_sleep(2);
      }
      __syncthreads();
      int lo = rev ? (T_OUT - (ci + 1) * TC) : (ci * TC);
      f16* Cbuf = (ci & 1) ? xgB : xgA;
      const f16* Ap0 = act + ((size_t)(row0 / TC) * T_OUT + lo + row0 % TC) * HDIM + ak;
      const f16* Ap1 = act + ((size_t)(row1 / TC) * T_OUT + lo + row1 % TC) * HDIM + ak;
      const float* Bp = Wi + (size_t)(2 * bk) * GDIM + n0 + bn;
      f16x4 ra0 = {}, ra1 = {};
      float4 rb0 = {}, rb1 = {};
      if (valid) {
        ra0 = *(const f16x4*)Ap0;
        ra1 = *(const f16x4*)Ap1;
        rb0 = *(const float4*)Bp;
        rb1 = *(const float4*)(Bp + (size_t)GDIM);
      }
      float acc[8][8];
#pragma unroll
      for (int i = 0; i < 8; ++i)
#pragma unroll
        for (int j = 0; j < 8; ++j) acc[i][j] = 0.f;
      for (int kt = 0; kt < 24; ++kt) {
        if (valid) {
          int ak2 = ak >> 1;
          As2[(ak2 + 0) * 136 + am] = (f16x2){ra0[0], ra0[1]};
          As2[(ak2 + 1) * 136 + am] = (f16x2){ra0[2], ra0[3]};
          As2[(ak2 + 0) * 136 + am + 64] = (f16x2){ra1[0], ra1[1]};
          As2[(ak2 + 1) * 136 + am + 64] = (f16x2){ra1[2], ra1[3]};
          Bs2[bk * 128 + bn + 0] = (f16x2){(f16)rb0.x, (f16)rb1.x};
          Bs2[bk * 128 + bn + 1] = (f16x2){(f16)rb0.y, (f16)rb1.y};
          Bs2[bk * 128 + bn + 2] = (f16x2){(f16)rb0.z, (f16)rb1.z};
          Bs2[bk * 128 + bn + 3] = (f16x2){(f16)rb0.w, (f16)rb1.w};
        }
        __syncthreads();
        if (valid) {
          if (kt < 23) {
            Ap0 += 16; Ap1 += 16; Bp += (size_t)16 * GDIM;
            ra0 = *(const f16x4*)Ap0;
            ra1 = *(const f16x4*)Ap1;
            rb0 = *(const float4*)Bp;
            rb1 = *(const float4*)(Bp + (size_t)GDIM);
          }
#pragma unroll
          for (int k2i = 0; k2i < 8; ++k2i) {
            f16x8 a0 = *(const f16x8*)&As2[k2i * 136 + ty * 4];
            f16x8 a1 = *(const f16x8*)&As2[k2i * 136 + 64 + ty * 4];
            f16x8 b0 = *(const f16x8*)&Bs2[k2i * 128 + tx * 4];
            f16x8 b1 = *(const f16x8*)&Bs2[k2i * 128 + 64 + tx * 4];
            f16x2 av[8], bv[8];
#pragma unroll
            for (int qq = 0; qq < 4; ++qq) {
              av[qq] = (f16x2){a0[2 * qq], a0[2 * qq + 1]};
              av[qq + 4] = (f16x2){a1[2 * qq], a1[2 * qq + 1]};
              bv[qq] = (f16x2){b0[2 * qq], b0[2 * qq + 1]};
              bv[qq + 4] = (f16x2){b1[2 * qq], b1[2 * qq + 1]};
            }
#pragma unroll
            for (int i = 0; i < 8; ++i)
#pragma unroll
              for (int j = 0; j < 8; ++j) acc[i][j] = fdot2(av[i], bv[j], acc[i][j]);
          }
        }
        __syncthreads();
      }
      if (valid) {
#pragma unroll
        for (int i = 0; i < 8; ++i) {
          int mi = (i < 4) ? (ty * 4 + i) : (64 + ty * 4 + i - 4);
          f16* Cp = Cbuf + (size_t)(m0 + mi) * GDIM + n0;
          f16x4 p0, p1;
          p0[0] = (f16)acc[i][0]; p0[1] = (f16)acc[i][1]; p0[2] = (f16)acc[i][2]; p0[3] = (f16)acc[i][3];
          p1[0] = (f16)acc[i][4]; p1[1] = (f16)acc[i][5]; p1[2] = (f16)acc[i][6]; p1[3] = (f16)acc[i][7];
          u32x2 q0 = __builtin_bit_cast(u32x2, p0);
          u32x2 q1 = __builtin_bit_cast(u32x2, p1);
          asm volatile("global_store_dwordx2 %0, %2, off sc0 sc1\n\t"
                       "global_store_dwordx2 %1, %3, off sc0 sc1"
                       :: "v"(Cp + tx * 4), "v"(Cp + 64 + tx * 4), "v"(q0), "v"(q1)
                       : "memory");
        }
      }
      asm volatile("s_waitcnt vmcnt(0)" ::: "memory");
      __syncthreads();
      if (tid == 0)
        __hip_atomic_fetch_add(&ctr2[1], 1u, __ATOMIC_RELAXED, __HIP_MEMORY_SCOPE_AGENT);
    }
  }
}

// ---------------------------------------------------------------------------
// dense: out(204800,5) = h(204800,384 fp16) @ W(384,5) + b  (fp32 out)
// ---------------------------------------------------------------------------
__global__ __launch_bounds__(256) void dense_kernel(
    const f16* __restrict__ h, const float* __restrict__ dw,
    const float* __restrict__ db, float* __restrict__ out) {
  __shared__ float ws_[1920];
  __shared__ float bs[5];
  int tid = threadIdx.x;
  for (int i = tid; i < 1920; i += 256) ws_[i] = dw[i];
  if (tid < 5) bs[tid] = db[tid];
  __syncthreads();
  size_t flat = (size_t)blockIdx.x * 256 + tid;
  const f16* hp = h + flat * HDIM;
  float acc[5];
#pragma unroll
  for (int o = 0; o < 5; ++o) acc[o] = bs[o];
  for (int d = 0; d < HDIM; d += 4) {
    f16x4 hv = *(const f16x4*)(hp + d);
#pragma unroll
    for (int o = 0; o < 5; ++o) {
      acc[o] = fmaf((float)hv[0], ws_[(d + 0) * 5 + o], acc[o]);
      acc[o] = fmaf((float)hv[1], ws_[(d + 1) * 5 + o], acc[o]);
      acc[o] = fmaf((float)hv[2], ws_[(d + 2) * 5 + o], acc[o]);
      acc[o] = fmaf((float)hv[3], ws_[(d + 3) * 5 + o], acc[o]);
    }
  }
  float* op = out + flat * 5;
#pragma unroll
  for (int o = 0; o < 5; ++o) op[o] = acc[o];
}

// ---------------------------------------------------------------------------
extern "C" void kernel_launch(void* const* d_in, const int* in_sizes, int n_in,
                              void* d_out, int out_size, void* d_ws, size_t ws_size,
                              hipStream_t stream) {
  const float* x  = (const float*)d_in[0];
  const float* w1 = (const float*)d_in[1];
  const float* b1 = (const float*)d_in[2];
  const float* w2 = (const float*)d_in[3];
  const float* b2 = (const float*)d_in[4];
  const float* w3 = (const float*)d_in[5];
  const float* b3 = (const float*)d_in[6];
  const float* Wi = (const float*)d_in[7];
  const float* Wh = (const float*)d_in[8];
  const float* lb = (const float*)d_in[9];
  const float* dw = (const float*)d_in[10];
  const float* db = (const float*)d_in[11];
  float* out = (float*)d_out;
  char* ws = (char*)d_ws;

  // ws (~195.2 MB <= proven 197): act | xgcA | xgcB | whB | xh | ctr | w3t
  const size_t ACT_BYTES = (size_t)B_SZ * T_OUT * HDIM * 2;   // 157.3 MB
  const size_t XGC_BYTES = (size_t)B_SZ * TC * GDIM * 2;      // 15.7 MB each
  const size_t WHB_BYTES = (size_t)5 * 8 * 12 * 12 * 64 * 16; // 5.9 MB
  const size_t XH_BYTES  = (size_t)2 * 128 * 64 * 16;         // 256 KB
  const size_t CTR_BYTES = 64;                                // 5 layers x 2 ctrs
  f16*      act  = (f16*)ws;
  f16*      xgcA = (f16*)(ws + ACT_BYTES);
  f16*      xgcB = (f16*)(ws + ACT_BYTES + XGC_BYTES);
  f16*      whB  = (f16*)(ws + ACT_BYTES + 2 * XGC_BYTES);
  unsigned* xh   = (unsigned*)(ws + ACT_BYTES + 2 * XGC_BYTES + WHB_BYTES);
  unsigned* ctr  = (unsigned*)(ws + ACT_BYTES + 2 * XGC_BYTES + WHB_BYTES + XH_BYTES);
  f16*      w3t  = (f16*)(ws + ACT_BYTES + 2 * XGC_BYTES + WHB_BYTES + XH_BYTES + CTR_BYTES);
  f16* y2 = xgcA;  // alias: consumed before xgc/whB are written

  hipMemsetAsync(xh, 0, XH_BYTES + CTR_BYTES, stream);  // tags + counters

  hipLaunchKernelGGL(conv12_kernel, dim3(B_SZ * T_IN / 256), dim3(256), 0, stream,
                     x, w1, b1, w2, b2, y2);
  hipLaunchKernelGGL(w3cvt_kernel, dim3(384 * 320 / 256), dim3(256), 0, stream,
                     w3, w3t);
  hipLaunchKernelGGL(conv3_kernel, dim3(T_OUT / C3M, B_SZ), dim3(384), 0, stream,
                     y2, w3t, b3, act);
  hipLaunchKernelGGL(whcvt_kernel, dim3((unsigned)(WHB_BYTES / 4 / 256)), dim3(256), 0, stream,
                     Wh, (f16x2*)whB);

  for (int l = 0; l < 5; ++l) {
    int rev = (l % 2 == 0) ? 1 : 0;
    const float* wi_p = Wi + (size_t)l * HDIM * GDIM;
    const f16* wh_p = whB + (size_t)l * 8 * 12 * 12 * 64 * 8;
    const float* lb_p = lb + (size_t)l * GDIM;
    hipLaunchKernelGGL(fused_layer_kernel, dim3(256), dim3(768), 0, stream,
                       xgcA, xgcB, wh_p, lb_p, act, wi_p, xh, ctr + l * 2,
                       rev, l * NCHUNK);
  }
  hipLaunchKernelGGL(dense_kernel, dim3((B_SZ * T_OUT) / 256), dim3(256), 0, stream,
                     act, dw, db, out);
}

// Round 10
// 27041.251 us; speedup vs baseline: 1.3793x; 1.0769x over previous
//
#include <hip/hip_runtime.h>
#include <math.h>

#define B_SZ 128
#define T_IN 8000
#define T_OUT 1600
#define HDIM 384
#define GDIM 1536   // 4*H
#define TC 40       // time chunk
#define NCHUNK (T_OUT / TC)   // 40
#define NTILES (12 * (B_SZ * TC / 128))   // 480 gemm tiles per chunk
#define NLB 64            // LSTM blocks: 8 groups x 8 column-slices

typedef _Float16 f16;
typedef __attribute__((ext_vector_type(2))) _Float16 f16x2;
typedef __attribute__((ext_vector_type(4))) _Float16 f16x4;
typedef __attribute__((ext_vector_type(8))) _Float16 f16x8;
typedef __attribute__((ext_vector_type(4))) float f32x4;
typedef __attribute__((ext_vector_type(4))) unsigned int u32x4;

__device__ inline float fdot2(f16x2 a, f16x2 b, float c) {
#if __has_builtin(__builtin_amdgcn_fdot2)
  return __builtin_amdgcn_fdot2(a, b, c, false);
#else
  return fmaf((float)a[0], (float)b[0], fmaf((float)a[1], (float)b[1], c));
#endif
}

__device__ inline float rcp_fast(float x) {
#if __has_builtin(__builtin_amdgcn_rcpf)
  return __builtin_amdgcn_rcpf(x);
#else
  return 1.f / x;
#endif
}
__device__ inline float sigf(float z) { return rcp_fast(1.f + __expf(-z)); }
__device__ inline float tanh_fast(float z) {
  z = fminf(fmaxf(z, -15.f), 15.f);
  float e = __expf(2.f * z);
  return (e - 1.f) * rcp_fast(e + 1.f);
}

// ---------------------------------------------------------------------------
// conv1 (5,1,4) + silu + conv2 (5,4,16) + silu, fused. One thread per (b,t).
// ---------------------------------------------------------------------------
__global__ __launch_bounds__(256) void conv12_kernel(
    const float* __restrict__ x, const float* __restrict__ w1, const float* __restrict__ b1,
    const float* __restrict__ w2, const float* __restrict__ b2, f16* __restrict__ y2) {
  __shared__ float sw1[20], sb1[4], sw2[320], sb2[16];
  int tid = threadIdx.x;
  if (tid < 20) sw1[tid] = w1[tid];
  if (tid < 4)  sb1[tid] = b1[tid];
  if (tid < 16) sb2[tid] = b2[tid];
  for (int i = tid; i < 320; i += 256) sw2[i] = w2[i];
  __syncthreads();
  int flat = blockIdx.x * 256 + tid;
  int b = flat / T_IN, t = flat % T_IN;
  const float* xb = x + (size_t)b * T_IN;
  float xv[9];
#pragma unroll
  for (int d = 0; d < 9; ++d) {
    int tt = t + d - 4;
    xv[d] = (tt >= 0 && tt < T_IN) ? xb[tt] : 0.f;
  }
  float y1[5][4];
#pragma unroll
  for (int u = 0; u < 5; ++u) {
    int tau = t + u - 2;
    bool valid = (tau >= 0 && tau < T_IN);
#pragma unroll
    for (int co = 0; co < 4; ++co) {
      float a = sb1[co];
#pragma unroll
      for (int k = 0; k < 5; ++k) a = fmaf(xv[u + k], sw1[k * 4 + co], a);
      y1[u][co] = valid ? (a / (1.f + expf(-a))) : 0.f;
    }
  }
  f16x8 o0, o1;
#pragma unroll
  for (int co = 0; co < 16; ++co) {
    float a = sb2[co];
#pragma unroll
    for (int u = 0; u < 5; ++u)
#pragma unroll
      for (int ci = 0; ci < 4; ++ci)
        a = fmaf(y1[u][ci], sw2[(u * 4 + ci) * 16 + co], a);
    float sv = a / (1.f + expf(-a));
    if (co < 8) o0[co] = (f16)sv; else o1[co - 8] = (f16)sv;
  }
  f16x8* dst = (f16x8*)(y2 + (size_t)flat * 16);
  dst[0] = o0;
  dst[1] = o1;
}

// ---------------------------------------------------------------------------
// w3 -> transposed f16 [c][k] (K padded 304->320 with zeros).
// ---------------------------------------------------------------------------
__global__ __launch_bounds__(256) void w3cvt_kernel(
    const float* __restrict__ w3, f16* __restrict__ w3t) {
  int idx = blockIdx.x * 256 + threadIdx.x;   // 384*320 = 122880
  int c = idx / 320, k = idx - c * 320;
  w3t[idx] = (k < 304) ? (f16)w3[(size_t)k * 384 + c] : (f16)0.f;
}

// ---------------------------------------------------------------------------
// conv3 via MFMA (verified round 6).
// ---------------------------------------------------------------------------
#define C3M 32
#define C3K 320
#define INSP 24
#define BSTP 40

__global__ __launch_bounds__(384) void conv3_kernel(
    const f16* __restrict__ y2, const f16* __restrict__ w3t,
    const float* __restrict__ b3, f16* __restrict__ act) {
  __shared__ f16 in_s[176 * INSP];
  __shared__ f16 bs_t[384 * BSTP];
  int tid = threadIdx.x;
  int b = blockIdx.y;
  int t0 = blockIdx.x * C3M;
  int base_t = t0 * 5 - 7;
  for (int j = tid; j < 352; j += 384) {
    int tau = j >> 1, ci0 = (j & 1) * 8;
    int tt = base_t + tau;
    f16x8 v = {};
    if (tt >= 0 && tt < T_IN)
      v = *(const f16x8*)(y2 + ((size_t)b * T_IN + tt) * 16 + ci0);
    *(f16x8*)&in_s[tau * INSP + ci0] = v;
  }
  int wv = tid >> 6;
  int l = tid & 63;
  int lm = l & 15;
  int lk = l >> 4;
  f32x4 acc[2][4];
#pragma unroll
  for (int mt = 0; mt < 2; ++mt)
#pragma unroll
    for (int q = 0; q < 4; ++q) acc[mt][q] = (f32x4){0.f, 0.f, 0.f, 0.f};
  for (int ks = 0; ks < 10; ++ks) {
    __syncthreads();
    for (int u = tid; u < 1536; u += 384) {
      int c = u >> 2, k8 = u & 3;
      *(f16x8*)&bs_t[c * BSTP + k8 * 8] =
          *(const f16x8*)(w3t + (size_t)c * C3K + ks * 32 + k8 * 8);
    }
    __syncthreads();
    int kg = ks * 32 + lk * 8;
    int kk = kg >> 4, ci = kg & 15;
    f16x8 a0 = *(const f16x8*)&in_s[(lm * 5 + kk) * INSP + ci];
    f16x8 a1 = *(const f16x8*)&in_s[((lm + 16) * 5 + kk) * INSP + ci];
#pragma unroll
    for (int q = 0; q < 4; ++q) {
      f16x8 bf = *(const f16x8*)&bs_t[((wv * 4 + q) * 16 + lm) * BSTP + lk * 8];
      acc[0][q] = __builtin_amdgcn_mfma_f32_16x16x32_f16(a0, bf, acc[0][q], 0, 0, 0);
      acc[1][q] = __builtin_amdgcn_mfma_f32_16x16x32_f16(a1, bf, acc[1][q], 0, 0, 0);
    }
  }
#pragma unroll
  for (int mt = 0; mt < 2; ++mt)
#pragma unroll
    for (int q = 0; q < 4; ++q) {
      int n = (wv * 4 + q) * 16 + lm;
      float bv = b3[n];
#pragma unroll
      for (int r = 0; r < 4; ++r) {
        int m = mt * 16 + lk * 4 + r;
        float a = acc[mt][q][r] + bv;
        a = a / (1.f + expf(-a));
        act[((size_t)b * T_OUT + t0 + m) * HDIM + n] = (f16)a;
      }
    }
}

// ---------------------------------------------------------------------------
// Wh -> MFMA B-fragment repack (8-slice layout, verified round 3).
// ---------------------------------------------------------------------------
__global__ __launch_bounds__(256) void whcvt_kernel(
    const float* __restrict__ Wh, f16x2* __restrict__ whB) {
  size_t idx = (size_t)blockIdx.x * 256 + threadIdx.x;
  int d = (int)(idx & 3);
  size_t r1 = idx >> 2;
  int lane = (int)(r1 & 63);
  size_t r2 = r1 >> 6;
  int ks = (int)(r2 % 12);
  size_t r3 = r2 / 12;
  int nt = (int)(r3 % 12);
  size_t r4 = r3 / 12;
  int isl = (int)(r4 & 7);
  int L = (int)(r4 >> 3);
  int cz = nt * 16 + (lane & 15);
  int gate = cz & 3;
  int jj = cz >> 2;
  int gcol = gate * 384 + isl * 48 + jj;
  int k2d = ks * 16 + (lane >> 4) * 4 + d;
  const float* src = Wh + ((size_t)L * 384 + 2 * k2d) * 1536 + gcol;
  f16x2 v;
  v[0] = (f16)src[0];
  v[1] = (f16)src[1536];
  whB[idx] = v;
}

// ---------------------------------------------------------------------------
// Standalone chunked xg GEMM (primes chunk 0 of each layer).
// ---------------------------------------------------------------------------
__global__ __launch_bounds__(256) void gemm_xg_kernel(
    const f16* __restrict__ act, const float* __restrict__ Bw,
    f16* __restrict__ C, int lo) {
  __shared__ f16x2 As2[8 * 136];
  __shared__ f16x2 Bs2[8 * 128];
  int tid = threadIdx.x;
  int n0 = blockIdx.x * 128;
  int m0 = blockIdx.y * 128;
  int am = tid >> 2;
  int ak = (tid & 3) * 4;
  int bk = tid >> 5;
  int bn = (tid & 31) * 4;
  int row0 = m0 + am, row1 = row0 + 64;
  const f16* Ap0 = act + ((size_t)(row0 / TC) * T_OUT + lo + row0 % TC) * HDIM + ak;
  const f16* Ap1 = act + ((size_t)(row1 / TC) * T_OUT + lo + row1 % TC) * HDIM + ak;
  const float* Bp = Bw + (size_t)(2 * bk) * GDIM + n0 + bn;
  f16x4 ra0 = *(const f16x4*)Ap0;
  f16x4 ra1 = *(const f16x4*)Ap1;
  float4 rb0 = *(const float4*)Bp;
  float4 rb1 = *(const float4*)(Bp + (size_t)GDIM);
  float acc[8][8];
#pragma unroll
  for (int i = 0; i < 8; ++i)
#pragma unroll
    for (int j = 0; j < 8; ++j) acc[i][j] = 0.f;
  int tx = tid & 15, ty = tid >> 4;
  for (int kt = 0; kt < 24; ++kt) {
    int ak2 = ak >> 1;
    As2[(ak2 + 0) * 136 + am] = (f16x2){ra0[0], ra0[1]};
    As2[(ak2 + 1) * 136 + am] = (f16x2){ra0[2], ra0[3]};
    As2[(ak2 + 0) * 136 + am + 64] = (f16x2){ra1[0], ra1[1]};
    As2[(ak2 + 1) * 136 + am + 64] = (f16x2){ra1[2], ra1[3]};
    Bs2[bk * 128 + bn + 0] = (f16x2){(f16)rb0.x, (f16)rb1.x};
    Bs2[bk * 128 + bn + 1] = (f16x2){(f16)rb0.y, (f16)rb1.y};
    Bs2[bk * 128 + bn + 2] = (f16x2){(f16)rb0.z, (f16)rb1.z};
    Bs2[bk * 128 + bn + 3] = (f16x2){(f16)rb0.w, (f16)rb1.w};
    __syncthreads();
    if (kt < 23) {
      Ap0 += 16; Ap1 += 16; Bp += (size_t)16 * GDIM;
      ra0 = *(const f16x4*)Ap0;
      ra1 = *(const f16x4*)Ap1;
      rb0 = *(const float4*)Bp;
      rb1 = *(const float4*)(Bp + (size_t)GDIM);
    }
#pragma unroll
    for (int k2 = 0; k2 < 8; ++k2) {
      f16x8 a0 = *(const f16x8*)&As2[k2 * 136 + ty * 4];
      f16x8 a1 = *(const f16x8*)&As2[k2 * 136 + 64 + ty * 4];
      f16x8 b0 = *(const f16x8*)&Bs2[k2 * 128 + tx * 4];
      f16x8 b1 = *(const f16x8*)&Bs2[k2 * 128 + 64 + tx * 4];
      f16x2 av[8], bv[8];
#pragma unroll
      for (int q = 0; q < 4; ++q) {
        av[q] = (f16x2){a0[2 * q], a0[2 * q + 1]};
        av[q + 4] = (f16x2){a1[2 * q], a1[2 * q + 1]};
        bv[q] = (f16x2){b0[2 * q], b0[2 * q + 1]};
        bv[q + 4] = (f16x2){b1[2 * q], b1[2 * q + 1]};
      }
#pragma unroll
      for (int i = 0; i < 8; ++i)
#pragma unroll
        for (int j = 0; j < 8; ++j) acc[i][j] = fdot2(av[i], bv[j], acc[i][j]);
    }
    __syncthreads();
  }
#pragma unroll
  for (int i = 0; i < 8; ++i) {
    int mi = (i < 4) ? (ty * 4 + i) : (64 + ty * 4 + i - 4);
    f16* Cp = C + (size_t)(m0 + mi) * GDIM + n0;
    f16x4 p0, p1;
    p0[0] = (f16)acc[i][0]; p0[1] = (f16)acc[i][1]; p0[2] = (f16)acc[i][2]; p0[3] = (f16)acc[i][3];
    p1[0] = (f16)acc[i][4]; p1[1] = (f16)acc[i][5]; p1[2] = (f16)acc[i][6]; p1[3] = (f16)acc[i][7];
    *(f16x4*)(Cp + tx * 4) = p0;
    *(f16x4*)(Cp + 64 + tx * 4) = p1;
  }
}

// ---------------------------------------------------------------------------
// FUSED kernel: 256 blocks x 768 threads.
//  blocks 0..63: systolic LSTM (round-7 dataflow + tag-in-payload protocol,
//    measured 124us/dispatch, verified absmax 1.9e-6). ONE change this round:
//    the first poll load is ISSUED immediately after publish (no waitcnt) so
//    its LLC RTT overlaps the act store + xg prefetch; vmcnt(0)+sched_barrier
//    then tag-check (rule #18 fence). Retry loop unchanged.
//  blocks 64..255: GEMM for next chunk at lo_g; 3 sub-tiles/block.
// ---------------------------------------------------------------------------
#define HSTR 784   // padded h2s row stride in bytes (768 data + 16 pad)

union FusedSh {
  struct { char h2s[16 * HSTR]; unsigned pub[16 * 25]; } L;    // 12544+1600 B
  struct { f16x2 As2[3][8 * 136]; f16x2 Bs2[3][8 * 128]; } G;  // 25344 B
  char pad[25600];
};

__global__ __launch_bounds__(768, 1) void fused_kernel(
    const f16* __restrict__ xgc_rd, f16* __restrict__ xgc_wr,
    const f16* __restrict__ whB, const float* __restrict__ bias,
    f16* __restrict__ act, float* __restrict__ cst, const float* __restrict__ Wi,
    unsigned* __restrict__ xh,
    int lo_l, int lo_g, int reverse, int first, int do_gemm, int epoch) {
  __shared__ FusedSh sh;
  int tid = threadIdx.x;

  if (blockIdx.x < NLB) {
    // ================= systolic LSTM branch (MFMA) =================
    int wid = blockIdx.x;
    int g = wid & 7;             // group 0..7 (16 batches)
    int isl = wid >> 3;          // column slice 0..7 (48 h-cols)
    int b0 = g * 16;
    int nt = tid >> 6;           // wave id == N-tile 0..11
    int l = tid & 63;
    int bg = l >> 4;             // C-frag row group: batches bg*4..bg*4+3
    int qj = (l >> 2) & 3;       // jj offset within tile
    int gate = l & 3;
    int jj = nt * 4 + qj;        // 0..47
    int hcol = isl * 48 + jj;
    int gcol = gate * 384 + isl * 48 + jj;

    // --- B-frag weights -> 48 VGPRs, loaded once, pinned ---
    f16x8 wreg[12];
    {
      const f16x8* wp = (const f16x8*)whB + (size_t)(isl * 12 + nt) * 12 * 64 + l;
#pragma unroll
      for (int ks = 0; ks < 12; ++ks) wreg[ks] = wp[(size_t)ks * 64];
#pragma unroll
      for (int ks = 0; ks < 12; ++ks) asm volatile("" : "+v"(wreg[ks]));
    }
    float bias_own = bias[gcol];

    float c_reg[4];
    if (first) {
#pragma unroll
      for (int r = 0; r < 4; ++r) c_reg[r] = 0.f;
      for (int i = tid; i < 16 * HSTR / 16; i += 768)
        *(f16x8*)(sh.L.h2s + i * 16) = (f16x8){};
    } else {
      int tprev = reverse ? (lo_l + TC) : (lo_l - 1);
#pragma unroll
      for (int r = 0; r < 4; ++r)
        c_reg[r] = cst[(size_t)(b0 + bg * 4 + r) * HDIM + hcol];
      int flat = tid * 8;
      int bt = flat / 384, c0 = flat % 384;
      *(f16x8*)(sh.L.h2s + bt * HSTR + c0 * 2) =
          *(const f16x8*)(act + ((size_t)(b0 + bt) * T_OUT + tprev) * HDIM + c0);
    }
    __syncthreads();

    const char* arow = sh.L.h2s + (l & 15) * HSTR + (l >> 4) * 16;
    unsigned short* pubh = (unsigned short*)sh.L.pub;

    // second gather unit (1024 units over 768 threads, spread across waves)
    int k2 = (tid % 3 == 0) ? (768 + tid / 3) : -1;

    // xg preload for step 0
    float xv[4];
    {
      int tl0 = reverse ? (TC - 1) : 0;
      const f16* xb = xgc_rd + ((size_t)(b0 + bg * 4) * TC + tl0) * GDIM + gcol;
#pragma unroll
      for (int r = 0; r < 4; ++r) xv[r] = (float)xb[(size_t)r * TC * GDIM];
    }

    for (int s = 0; s < TC; ++s) {
      int t = reverse ? (lo_l + TC - 1 - s) : (lo_l + s);

      // --- z = h @ Wslice via MFMA (full K per wave, no reduction) ---
      f32x4 acc = {0.f, 0.f, 0.f, 0.f};
#pragma unroll
      for (int ks = 0; ks < 12; ++ks) {
        f16x8 a = *(const f16x8*)(arow + ks * 64);
        acc = __builtin_amdgcn_mfma_f32_16x16x32_f16(a, wreg[ks], acc, 0, 0, 0);
      }

      // --- gates: quad butterfly distributes all 4 gates of (jj, 4 batches) ---
      f16 h16[4];
#pragma unroll
      for (int r = 0; r < 4; ++r) {
        float a = acc[r] + xv[r] + bias_own;
        float b = __shfl_xor(a, 1);
        float cc = __shfl_xor(a, 2);
        float dd = __shfl_xor(b, 2);
        float zi = (gate == 0) ? a : (gate == 1) ? b : (gate == 2) ? cc : dd;
        float zf = (gate == 1) ? a : (gate == 0) ? b : (gate == 3) ? cc : dd;
        float zg = (gate == 2) ? a : (gate == 3) ? b : (gate == 0) ? cc : dd;
        float zo = (gate == 3) ? a : (gate == 2) ? b : (gate == 1) ? cc : dd;
        float ig = sigf(zi), fg = sigf(zf), gv = tanh_fast(zg), og = sigf(zo);
        c_reg[r] = fg * c_reg[r] + ig * gv;
        h16[r] = (f16)(og * tanh_fast(c_reg[r]));
      }

      if (s + 1 < TC) {
        unsigned tag = (unsigned)(epoch * TC + s + 1);
        unsigned* slotbase = xh + (size_t)(s & 1) * 128 * 256;

        // --- stage own h slice into LDS pub (rows=batch, 24 pair-words) ---
        if (gate == 0) {
          int lcol = nt * 4 + qj;
#pragma unroll
          for (int r = 0; r < 4; ++r)
            pubh[(bg * 4 + r) * 50 + lcol] = __builtin_bit_cast(unsigned short, h16[r]);
        }
        __syncthreads();  // barrier A: pub staged (MFMA h2s reads also done)

        // --- publish: 128 threads x one 16B unit (3 data words + tag) ---
        if (tid < 128) {
          int bt = tid >> 3, u = tid & 7;
          const unsigned* pw = sh.L.pub + bt * 25 + u * 3;
          u32x4 dnew;
          dnew[0] = pw[0]; dnew[1] = pw[1]; dnew[2] = pw[2]; dnew[3] = tag;
          u32x4* dp = (u32x4*)(slotbase + (((size_t)(b0 + bt) * 64) + isl * 8 + u) * 4);
          asm volatile("global_store_dwordx4 %0, %1, off sc0 sc1"
                       :: "v"(dp), "v"(dnew) : "memory");
        }

        // --- select gather units; copy own-slice via LDS ---
        const u32x4* upA = nullptr; const u32x4* upB = nullptr;
        unsigned* dstA = nullptr; unsigned* dstB = nullptr;
#pragma unroll
        for (int uu = 0; uu < 2; ++uu) {
          int k = (uu == 0) ? tid : k2;
          if (uu == 1 && k < 0) break;
          int bt = k >> 6, rem = k & 63;
          int isl_src = rem >> 3, u = rem & 7;
          unsigned* dst = (unsigned*)(sh.L.h2s + bt * HSTR + isl_src * 96 + u * 12);
          if (isl_src == isl) {
            const unsigned* pw = sh.L.pub + bt * 25 + u * 3;
            dst[0] = pw[0]; dst[1] = pw[1]; dst[2] = pw[2];
          } else {
            const u32x4* up = (const u32x4*)(slotbase + (((size_t)(b0 + bt) * 64) + rem) * 4);
            if (!upA) { upA = up; dstA = dst; } else { upB = up; dstB = dst; }
          }
        }

        // --- issue FIRST poll loads now (RTT overlaps act store + xg fetch)
        u32x4 v0, v1;
        if (upA)
          asm volatile("global_load_dwordx4 %0, %1, off sc0 sc1"
                       : "=v"(v0) : "v"(upA) : "memory");
        if (upB)
          asm volatile("global_load_dwordx4 %0, %1, off sc0 sc1"
                       : "=v"(v1) : "v"(upB) : "memory");

        // --- hidden under flight: act store + next-step xg prefetch ---
        if (gate == 0) {
#pragma unroll
          for (int r = 0; r < 4; ++r)
            act[((size_t)(b0 + bg * 4 + r) * T_OUT + t) * HDIM + hcol] = h16[r];
        }
        {
          int tl_n = reverse ? (TC - 2 - s) : (s + 1);
          const f16* xb = xgc_rd + ((size_t)(b0 + bg * 4) * TC + tl_n) * GDIM + gcol;
#pragma unroll
          for (int r = 0; r < 4; ++r) xv[r] = (float)xb[(size_t)r * TC * GDIM];
        }

        // --- complete poll: drain, check, retry if stale ---
        if (upA) {
          asm volatile("s_waitcnt vmcnt(0)" ::: "memory");
          __builtin_amdgcn_sched_barrier(0);
          if (!upB) {
            while (v0[3] < tag) {
              __builtin_amdgcn_s_sleep(1);
              asm volatile("global_load_dwordx4 %0, %1, off sc0 sc1\n\ts_waitcnt vmcnt(0)"
                           : "=v"(v0) : "v"(upA) : "memory");
              __builtin_amdgcn_sched_barrier(0);
            }
            dstA[0] = v0[0]; dstA[1] = v0[1]; dstA[2] = v0[2];
          } else {
            while (v0[3] < tag || v1[3] < tag) {
              __builtin_amdgcn_s_sleep(1);
              asm volatile("global_load_dwordx4 %0, %2, off sc0 sc1\n\t"
                           "global_load_dwordx4 %1, %3, off sc0 sc1\n\t"
                           "s_waitcnt vmcnt(0)"
                           : "=&v"(v0), "=&v"(v1) : "v"(upA), "v"(upB) : "memory");
              __builtin_amdgcn_sched_barrier(0);
            }
            dstA[0] = v0[0]; dstA[1] = v0[1]; dstA[2] = v0[2];
            dstB[0] = v1[0]; dstB[1] = v1[1]; dstB[2] = v1[2];
          }
        }
        __syncthreads();  // barrier B: h2s complete for next step
      } else {
        if (gate == 0) {
#pragma unroll
          for (int r = 0; r < 4; ++r)
            act[((size_t)(b0 + bg * 4 + r) * T_OUT + t) * HDIM + hcol] = h16[r];
        }
      }
    }
    if (gate == 0) {
#pragma unroll
      for (int r = 0; r < 4; ++r)
        cst[(size_t)(b0 + bg * 4 + r) * HDIM + hcol] = c_reg[r];
    }
  } else {
    // ================= GEMM worker branch =================
    if (!do_gemm) return;
    int wid = blockIdx.x - NLB;       // 0..191
    int sub = tid >> 8;               // 0..2 (wave-uniform)
    int stid = tid & 255;
    int tileid = wid + 192 * sub;     // 0..575
    bool valid = (tileid < NTILES);
    int tclamp = valid ? tileid : 0;
    int n0 = (tclamp % 12) * 128;
    int m0 = (tclamp / 12) * 128;
    f16x2* As2 = &sh.G.As2[sub][0];
    f16x2* Bs2 = &sh.G.Bs2[sub][0];
    int am = stid >> 2;
    int ak = (stid & 3) * 4;
    int bk = stid >> 5;
    int bn = (stid & 31) * 4;
    int row0 = m0 + am, row1 = row0 + 64;
    const f16* Ap0 = act + ((size_t)(row0 / TC) * T_OUT + lo_g + row0 % TC) * HDIM + ak;
    const f16* Ap1 = act + ((size_t)(row1 / TC) * T_OUT + lo_g + row1 % TC) * HDIM + ak;
    const float* Bp = Wi + (size_t)(2 * bk) * GDIM + n0 + bn;
    f16x4 ra0 = {}, ra1 = {};
    float4 rb0 = {}, rb1 = {};
    if (valid) {
      ra0 = *(const f16x4*)Ap0;
      ra1 = *(const f16x4*)Ap1;
      rb0 = *(const float4*)Bp;
      rb1 = *(const float4*)(Bp + (size_t)GDIM);
    }
    float acc[8][8];
#pragma unroll
    for (int i = 0; i < 8; ++i)
#pragma unroll
      for (int j = 0; j < 8; ++j) acc[i][j] = 0.f;
    int tx = stid & 15, ty = stid >> 4;
    for (int kt = 0; kt < 24; ++kt) {
      if (valid) {
        int ak2 = ak >> 1;
        As2[(ak2 + 0) * 136 + am] = (f16x2){ra0[0], ra0[1]};
        As2[(ak2 + 1) * 136 + am] = (f16x2){ra0[2], ra0[3]};
        As2[(ak2 + 0) * 136 + am + 64] = (f16x2){ra1[0], ra1[1]};
        As2[(ak2 + 1) * 136 + am + 64] = (f16x2){ra1[2], ra1[3]};
        Bs2[bk * 128 + bn + 0] = (f16x2){(f16)rb0.x, (f16)rb1.x};
        Bs2[bk * 128 + bn + 1] = (f16x2){(f16)rb0.y, (f16)rb1.y};
        Bs2[bk * 128 + bn + 2] = (f16x2){(f16)rb0.z, (f16)rb1.z};
        Bs2[bk * 128 + bn + 3] = (f16x2){(f16)rb0.w, (f16)rb1.w};
      }
      __syncthreads();
      if (valid) {
        if (kt < 23) {
          Ap0 += 16; Ap1 += 16; Bp += (size_t)16 * GDIM;
          ra0 = *(const f16x4*)Ap0;
          ra1 = *(const f16x4*)Ap1;
          rb0 = *(const float4*)Bp;
          rb1 = *(const float4*)(Bp + (size_t)GDIM);
        }
#pragma unroll
        for (int k2i = 0; k2i < 8; ++k2i) {
          f16x8 a0 = *(const f16x8*)&As2[k2i * 136 + ty * 4];
          f16x8 a1 = *(const f16x8*)&As2[k2i * 136 + 64 + ty * 4];
          f16x8 b0 = *(const f16x8*)&Bs2[k2i * 128 + tx * 4];
          f16x8 b1 = *(const f16x8*)&Bs2[k2i * 128 + 64 + tx * 4];
          f16x2 av[8], bv[8];
#pragma unroll
          for (int qq = 0; qq < 4; ++qq) {
            av[qq] = (f16x2){a0[2 * qq], a0[2 * qq + 1]};
            av[qq + 4] = (f16x2){a1[2 * qq], a1[2 * qq + 1]};
            bv[qq] = (f16x2){b0[2 * qq], b0[2 * qq + 1]};
            bv[qq + 4] = (f16x2){b1[2 * qq], b1[2 * qq + 1]};
          }
#pragma unroll
          for (int i = 0; i < 8; ++i)
#pragma unroll
            for (int j = 0; j < 8; ++j) acc[i][j] = fdot2(av[i], bv[j], acc[i][j]);
        }
      }
      __syncthreads();
    }
    if (valid) {
#pragma unroll
      for (int i = 0; i < 8; ++i) {
        int mi = (i < 4) ? (ty * 4 + i) : (64 + ty * 4 + i - 4);
        f16* Cp = xgc_wr + (size_t)(m0 + mi) * GDIM + n0;
        f16x4 p0, p1;
        p0[0] = (f16)acc[i][0]; p0[1] = (f16)acc[i][1]; p0[2] = (f16)acc[i][2]; p0[3] = (f16)acc[i][3];
        p1[0] = (f16)acc[i][4]; p1[1] = (f16)acc[i][5]; p1[2] = (f16)acc[i][6]; p1[3] = (f16)acc[i][7];
        *(f16x4*)(Cp + tx * 4) = p0;
        *(f16x4*)(Cp + 64 + tx * 4) = p1;
      }
    }
  }
}

// ---------------------------------------------------------------------------
// dense: out(204800,5) = h(204800,384 fp16) @ W(384,5) + b  (fp32 out)
// ---------------------------------------------------------------------------
__global__ __launch_bounds__(256) void dense_kernel(
    const f16* __restrict__ h, const float* __restrict__ dw,
    const float* __restrict__ db, float* __restrict__ out) {
  __shared__ float ws_[1920];
  __shared__ float bs[5];
  int tid = threadIdx.x;
  for (int i = tid; i < 1920; i += 256) ws_[i] = dw[i];
  if (tid < 5) bs[tid] = db[tid];
  __syncthreads();
  size_t flat = (size_t)blockIdx.x * 256 + tid;
  const f16* hp = h + flat * HDIM;
  float acc[5];
#pragma unroll
  for (int o = 0; o < 5; ++o) acc[o] = bs[o];
  for (int d = 0; d < HDIM; d += 4) {
    f16x4 hv = *(const f16x4*)(hp + d);
#pragma unroll
    for (int o = 0; o < 5; ++o) {
      acc[o] = fmaf((float)hv[0], ws_[(d + 0) * 5 + o], acc[o]);
      acc[o] = fmaf((float)hv[1], ws_[(d + 1) * 5 + o], acc[o]);
      acc[o] = fmaf((float)hv[2], ws_[(d + 2) * 5 + o], acc[o]);
      acc[o] = fmaf((float)hv[3], ws_[(d + 3) * 5 + o], acc[o]);
    }
  }
  float* op = out + flat * 5;
#pragma unroll
  for (int o = 0; o < 5; ++o) op[o] = acc[o];
}

// ---------------------------------------------------------------------------
extern "C" void kernel_launch(void* const* d_in, const int* in_sizes, int n_in,
                              void* d_out, int out_size, void* d_ws, size_t ws_size,
                              hipStream_t stream) {
  const float* x  = (const float*)d_in[0];
  const float* w1 = (const float*)d_in[1];
  const float* b1 = (const float*)d_in[2];
  const float* w2 = (const float*)d_in[3];
  const float* b2 = (const float*)d_in[4];
  const float* w3 = (const float*)d_in[5];
  const float* b3 = (const float*)d_in[6];
  const float* Wi = (const float*)d_in[7];
  const float* Wh = (const float*)d_in[8];
  const float* lb = (const float*)d_in[9];
  const float* dw = (const float*)d_in[10];
  const float* db = (const float*)d_in[11];
  float* out = (float*)d_out;
  char* ws = (char*)d_ws;

  // ws (~195.4 MB <= proven 197): act | xgcA | xgcB | whB | cst | xh | w3t
  const size_t ACT_BYTES = (size_t)B_SZ * T_OUT * HDIM * 2;   // 157.3 MB
  const size_t XGC_BYTES = (size_t)B_SZ * TC * GDIM * 2;      // 15.7 MB each
  const size_t WHB_BYTES = (size_t)5 * 8 * 12 * 12 * 64 * 16; // 5.9 MB
  const size_t CST_BYTES = (size_t)B_SZ * HDIM * 4;           // 196.6 KB
  const size_t XH_BYTES  = (size_t)2 * 128 * 64 * 16;         // 256 KB
  const size_t W3T_BYTES = (size_t)384 * 320 * 2;             // 240 KB
  f16*      act  = (f16*)ws;
  f16*      xgcA = (f16*)(ws + ACT_BYTES);
  f16*      xgcB = (f16*)(ws + ACT_BYTES + XGC_BYTES);
  f16*      whB  = (f16*)(ws + ACT_BYTES + 2 * XGC_BYTES);
  float*    cst  = (float*)(ws + ACT_BYTES + 2 * XGC_BYTES + WHB_BYTES);
  unsigned* xh   = (unsigned*)(ws + ACT_BYTES + 2 * XGC_BYTES + WHB_BYTES + CST_BYTES);
  f16*      w3t  = (f16*)(ws + ACT_BYTES + 2 * XGC_BYTES + WHB_BYTES + CST_BYTES + XH_BYTES);
  f16* y2 = xgcA;  // alias: consumed before xgc/whB are written

  hipMemsetAsync(xh, 0, XH_BYTES, stream);  // zero tags (monotonic from 1)

  hipLaunchKernelGGL(conv12_kernel, dim3(B_SZ * T_IN / 256), dim3(256), 0, stream,
                     x, w1, b1, w2, b2, y2);
  hipLaunchKernelGGL(w3cvt_kernel, dim3(384 * 320 / 256), dim3(256), 0, stream,
                     w3, w3t);
  hipLaunchKernelGGL(conv3_kernel, dim3(T_OUT / C3M, B_SZ), dim3(384), 0, stream,
                     y2, w3t, b3, act);
  hipLaunchKernelGGL(whcvt_kernel, dim3((unsigned)(WHB_BYTES / 4 / 256)), dim3(256), 0, stream,
                     Wh, (f16x2*)whB);

  for (int l = 0; l < 5; ++l) {
    int rev = (l % 2 == 0) ? 1 : 0;
    const float* wi_p = Wi + (size_t)l * HDIM * GDIM;
    const f16* wh_p = whB + (size_t)l * 8 * 12 * 12 * 64 * 8;
    const float* lb_p = lb + (size_t)l * GDIM;
    int lo0 = rev ? (T_OUT - TC) : 0;
    hipLaunchKernelGGL(gemm_xg_kernel, dim3(GDIM / 128, (B_SZ * TC) / 128), dim3(256), 0, stream,
                       act, wi_p, xgcA, lo0);
    for (int ci = 0; ci < NCHUNK; ++ci) {
      int lo_l = rev ? (T_OUT - (ci + 1) * TC) : (ci * TC);
      int do_gemm = (ci + 1 < NCHUNK) ? 1 : 0;
      int lo_g = do_gemm ? (rev ? (T_OUT - (ci + 2) * TC) : ((ci + 1) * TC)) : 0;
      f16* rd = (ci % 2 == 0) ? xgcA : xgcB;
      f16* wr = (ci % 2 == 0) ? xgcB : xgcA;
      int epoch = l * NCHUNK + ci;
      hipLaunchKernelGGL(fused_kernel, dim3(256), dim3(768), 0, stream,
                         rd, wr, wh_p, lb_p, act, cst, wi_p, xh,
                         lo_l, lo_g, rev, (ci == 0) ? 1 : 0, do_gemm, epoch);
    }
  }
  hipLaunchKernelGGL(dense_kernel, dim3((B_SZ * T_OUT) / 256), dim3(256), 0, stream,
                     act, dw, db, out);
}

// Round 11
// 26367.560 us; speedup vs baseline: 1.4145x; 1.0255x over previous
//
#include <hip/hip_runtime.h>
#include <math.h>

#define B_SZ 128
#define T_IN 8000
#define T_OUT 1600
#define HDIM 384
#define GDIM 1536   // 4*H
#define TC 40       // time chunk
#define NCHUNK (T_OUT / TC)   // 40
#define NTILES (12 * (B_SZ * TC / 128))   // 480 gemm tiles per chunk
#define NLB 64            // LSTM blocks: 8 groups x 8 column-slices

typedef _Float16 f16;
typedef __attribute__((ext_vector_type(2))) _Float16 f16x2;
typedef __attribute__((ext_vector_type(4))) _Float16 f16x4;
typedef __attribute__((ext_vector_type(8))) _Float16 f16x8;
typedef __attribute__((ext_vector_type(4))) float f32x4;
typedef __attribute__((ext_vector_type(4))) unsigned int u32x4;

__device__ inline float fdot2(f16x2 a, f16x2 b, float c) {
#if __has_builtin(__builtin_amdgcn_fdot2)
  return __builtin_amdgcn_fdot2(a, b, c, false);
#else
  return fmaf((float)a[0], (float)b[0], fmaf((float)a[1], (float)b[1], c));
#endif
}

__device__ inline float rcp_fast(float x) {
#if __has_builtin(__builtin_amdgcn_rcpf)
  return __builtin_amdgcn_rcpf(x);
#else
  return 1.f / x;
#endif
}
__device__ inline float sigf(float z) { return rcp_fast(1.f + __expf(-z)); }
__device__ inline float tanh_fast(float z) {
  z = fminf(fmaxf(z, -15.f), 15.f);
  float e = __expf(2.f * z);
  return (e - 1.f) * rcp_fast(e + 1.f);
}

// ---------------------------------------------------------------------------
// conv1 (5,1,4) + silu + conv2 (5,4,16) + silu, fused. One thread per (b,t).
// ---------------------------------------------------------------------------
__global__ __launch_bounds__(256) void conv12_kernel(
    const float* __restrict__ x, const float* __restrict__ w1, const float* __restrict__ b1,
    const float* __restrict__ w2, const float* __restrict__ b2, f16* __restrict__ y2) {
  __shared__ float sw1[20], sb1[4], sw2[320], sb2[16];
  int tid = threadIdx.x;
  if (tid < 20) sw1[tid] = w1[tid];
  if (tid < 4)  sb1[tid] = b1[tid];
  if (tid < 16) sb2[tid] = b2[tid];
  for (int i = tid; i < 320; i += 256) sw2[i] = w2[i];
  __syncthreads();
  int flat = blockIdx.x * 256 + tid;
  int b = flat / T_IN, t = flat % T_IN;
  const float* xb = x + (size_t)b * T_IN;
  float xv[9];
#pragma unroll
  for (int d = 0; d < 9; ++d) {
    int tt = t + d - 4;
    xv[d] = (tt >= 0 && tt < T_IN) ? xb[tt] : 0.f;
  }
  float y1[5][4];
#pragma unroll
  for (int u = 0; u < 5; ++u) {
    int tau = t + u - 2;
    bool valid = (tau >= 0 && tau < T_IN);
#pragma unroll
    for (int co = 0; co < 4; ++co) {
      float a = sb1[co];
#pragma unroll
      for (int k = 0; k < 5; ++k) a = fmaf(xv[u + k], sw1[k * 4 + co], a);
      y1[u][co] = valid ? (a / (1.f + expf(-a))) : 0.f;
    }
  }
  f16x8 o0, o1;
#pragma unroll
  for (int co = 0; co < 16; ++co) {
    float a = sb2[co];
#pragma unroll
    for (int u = 0; u < 5; ++u)
#pragma unroll
      for (int ci = 0; ci < 4; ++ci)
        a = fmaf(y1[u][ci], sw2[(u * 4 + ci) * 16 + co], a);
    float sv = a / (1.f + expf(-a));
    if (co < 8) o0[co] = (f16)sv; else o1[co - 8] = (f16)sv;
  }
  f16x8* dst = (f16x8*)(y2 + (size_t)flat * 16);
  dst[0] = o0;
  dst[1] = o1;
}

// ---------------------------------------------------------------------------
// w3 -> transposed f16 [c][k] (K padded 304->320 with zeros).
// ---------------------------------------------------------------------------
__global__ __launch_bounds__(256) void w3cvt_kernel(
    const float* __restrict__ w3, f16* __restrict__ w3t) {
  int idx = blockIdx.x * 256 + threadIdx.x;   // 384*320 = 122880
  int c = idx / 320, k = idx - c * 320;
  w3t[idx] = (k < 304) ? (f16)w3[(size_t)k * 384 + c] : (f16)0.f;
}

// ---------------------------------------------------------------------------
// conv3 via MFMA (verified round 6): per block one batch, 32 t-outputs x 384
// ch, K=320 (19 taps x 16 ch, zero-padded). Fragment mappings identical to
// the verified LSTM MFMA usage. in_s padded to 24 f16/row, bs_t to 40.
// ---------------------------------------------------------------------------
#define C3M 32
#define C3K 320
#define INSP 24
#define BSTP 40

__global__ __launch_bounds__(384) void conv3_kernel(
    const f16* __restrict__ y2, const f16* __restrict__ w3t,
    const float* __restrict__ b3, f16* __restrict__ act) {
  __shared__ f16 in_s[176 * INSP];
  __shared__ f16 bs_t[384 * BSTP];
  int tid = threadIdx.x;
  int b = blockIdx.y;
  int t0 = blockIdx.x * C3M;
  int base_t = t0 * 5 - 7;
  for (int j = tid; j < 352; j += 384) {
    int tau = j >> 1, ci0 = (j & 1) * 8;
    int tt = base_t + tau;
    f16x8 v = {};
    if (tt >= 0 && tt < T_IN)
      v = *(const f16x8*)(y2 + ((size_t)b * T_IN + tt) * 16 + ci0);
    *(f16x8*)&in_s[tau * INSP + ci0] = v;
  }
  int wv = tid >> 6;       // wave 0..5 -> N-tiles wv*4..wv*4+3
  int l = tid & 63;
  int lm = l & 15;
  int lk = l >> 4;
  f32x4 acc[2][4];
#pragma unroll
  for (int mt = 0; mt < 2; ++mt)
#pragma unroll
    for (int q = 0; q < 4; ++q) acc[mt][q] = (f32x4){0.f, 0.f, 0.f, 0.f};
  for (int ks = 0; ks < 10; ++ks) {
    __syncthreads();
    for (int u = tid; u < 1536; u += 384) {
      int c = u >> 2, k8 = u & 3;
      *(f16x8*)&bs_t[c * BSTP + k8 * 8] =
          *(const f16x8*)(w3t + (size_t)c * C3K + ks * 32 + k8 * 8);
    }
    __syncthreads();
    int kg = ks * 32 + lk * 8;
    int kk = kg >> 4, ci = kg & 15;
    f16x8 a0 = *(const f16x8*)&in_s[(lm * 5 + kk) * INSP + ci];
    f16x8 a1 = *(const f16x8*)&in_s[((lm + 16) * 5 + kk) * INSP + ci];
#pragma unroll
    for (int q = 0; q < 4; ++q) {
      f16x8 bf = *(const f16x8*)&bs_t[((wv * 4 + q) * 16 + lm) * BSTP + lk * 8];
      acc[0][q] = __builtin_amdgcn_mfma_f32_16x16x32_f16(a0, bf, acc[0][q], 0, 0, 0);
      acc[1][q] = __builtin_amdgcn_mfma_f32_16x16x32_f16(a1, bf, acc[1][q], 0, 0, 0);
    }
  }
#pragma unroll
  for (int mt = 0; mt < 2; ++mt)
#pragma unroll
    for (int q = 0; q < 4; ++q) {
      int n = (wv * 4 + q) * 16 + lm;
      float bv = b3[n];
#pragma unroll
      for (int r = 0; r < 4; ++r) {
        int m = mt * 16 + lk * 4 + r;
        float a = acc[mt][q][r] + bv;
        a = a / (1.f + expf(-a));
        act[((size_t)b * T_OUT + t0 + m) * HDIM + n] = (f16)a;
      }
    }
}

// ---------------------------------------------------------------------------
// Wh -> MFMA B-fragment repack (8-slice layout, verified round 3).
// ---------------------------------------------------------------------------
__global__ __launch_bounds__(256) void whcvt_kernel(
    const float* __restrict__ Wh, f16x2* __restrict__ whB) {
  size_t idx = (size_t)blockIdx.x * 256 + threadIdx.x;
  int d = (int)(idx & 3);
  size_t r1 = idx >> 2;
  int lane = (int)(r1 & 63);
  size_t r2 = r1 >> 6;
  int ks = (int)(r2 % 12);
  size_t r3 = r2 / 12;
  int nt = (int)(r3 % 12);
  size_t r4 = r3 / 12;
  int isl = (int)(r4 & 7);
  int L = (int)(r4 >> 3);
  int cz = nt * 16 + (lane & 15);
  int gate = cz & 3;
  int jj = cz >> 2;
  int gcol = gate * 384 + isl * 48 + jj;
  int k2d = ks * 16 + (lane >> 4) * 4 + d;
  const float* src = Wh + ((size_t)L * 384 + 2 * k2d) * 1536 + gcol;
  f16x2 v;
  v[0] = (f16)src[0];
  v[1] = (f16)src[1536];
  whB[idx] = v;
}

// ---------------------------------------------------------------------------
// Standalone chunked xg GEMM (primes chunk 0 of each layer).
// ---------------------------------------------------------------------------
__global__ __launch_bounds__(256) void gemm_xg_kernel(
    const f16* __restrict__ act, const float* __restrict__ Bw,
    f16* __restrict__ C, int lo) {
  __shared__ f16x2 As2[8 * 136];
  __shared__ f16x2 Bs2[8 * 128];
  int tid = threadIdx.x;
  int n0 = blockIdx.x * 128;
  int m0 = blockIdx.y * 128;
  int am = tid >> 2;
  int ak = (tid & 3) * 4;
  int bk = tid >> 5;
  int bn = (tid & 31) * 4;
  int row0 = m0 + am, row1 = row0 + 64;
  const f16* Ap0 = act + ((size_t)(row0 / TC) * T_OUT + lo + row0 % TC) * HDIM + ak;
  const f16* Ap1 = act + ((size_t)(row1 / TC) * T_OUT + lo + row1 % TC) * HDIM + ak;
  const float* Bp = Bw + (size_t)(2 * bk) * GDIM + n0 + bn;
  f16x4 ra0 = *(const f16x4*)Ap0;
  f16x4 ra1 = *(const f16x4*)Ap1;
  float4 rb0 = *(const float4*)Bp;
  float4 rb1 = *(const float4*)(Bp + (size_t)GDIM);
  float acc[8][8];
#pragma unroll
  for (int i = 0; i < 8; ++i)
#pragma unroll
    for (int j = 0; j < 8; ++j) acc[i][j] = 0.f;
  int tx = tid & 15, ty = tid >> 4;
  for (int kt = 0; kt < 24; ++kt) {
    int ak2 = ak >> 1;
    As2[(ak2 + 0) * 136 + am] = (f16x2){ra0[0], ra0[1]};
    As2[(ak2 + 1) * 136 + am] = (f16x2){ra0[2], ra0[3]};
    As2[(ak2 + 0) * 136 + am + 64] = (f16x2){ra1[0], ra1[1]};
    As2[(ak2 + 1) * 136 + am + 64] = (f16x2){ra1[2], ra1[3]};
    Bs2[bk * 128 + bn + 0] = (f16x2){(f16)rb0.x, (f16)rb1.x};
    Bs2[bk * 128 + bn + 1] = (f16x2){(f16)rb0.y, (f16)rb1.y};
    Bs2[bk * 128 + bn + 2] = (f16x2){(f16)rb0.z, (f16)rb1.z};
    Bs2[bk * 128 + bn + 3] = (f16x2){(f16)rb0.w, (f16)rb1.w};
    __syncthreads();
    if (kt < 23) {
      Ap0 += 16; Ap1 += 16; Bp += (size_t)16 * GDIM;
      ra0 = *(const f16x4*)Ap0;
      ra1 = *(const f16x4*)Ap1;
      rb0 = *(const float4*)Bp;
      rb1 = *(const float4*)(Bp + (size_t)GDIM);
    }
#pragma unroll
    for (int k2 = 0; k2 < 8; ++k2) {
      f16x8 a0 = *(const f16x8*)&As2[k2 * 136 + ty * 4];
      f16x8 a1 = *(const f16x8*)&As2[k2 * 136 + 64 + ty * 4];
      f16x8 b0 = *(const f16x8*)&Bs2[k2 * 128 + tx * 4];
      f16x8 b1 = *(const f16x8*)&Bs2[k2 * 128 + 64 + tx * 4];
      f16x2 av[8], bv[8];
#pragma unroll
      for (int q = 0; q < 4; ++q) {
        av[q] = (f16x2){a0[2 * q], a0[2 * q + 1]};
        av[q + 4] = (f16x2){a1[2 * q], a1[2 * q + 1]};
        bv[q] = (f16x2){b0[2 * q], b0[2 * q + 1]};
        bv[q + 4] = (f16x2){b1[2 * q], b1[2 * q + 1]};
      }
#pragma unroll
      for (int i = 0; i < 8; ++i)
#pragma unroll
        for (int j = 0; j < 8; ++j) acc[i][j] = fdot2(av[i], bv[j], acc[i][j]);
    }
    __syncthreads();
  }
#pragma unroll
  for (int i = 0; i < 8; ++i) {
    int mi = (i < 4) ? (ty * 4 + i) : (64 + ty * 4 + i - 4);
    f16* Cp = C + (size_t)(m0 + mi) * GDIM + n0;
    f16x4 p0, p1;
    p0[0] = (f16)acc[i][0]; p0[1] = (f16)acc[i][1]; p0[2] = (f16)acc[i][2]; p0[3] = (f16)acc[i][3];
    p1[0] = (f16)acc[i][4]; p1[1] = (f16)acc[i][5]; p1[2] = (f16)acc[i][6]; p1[3] = (f16)acc[i][7];
    *(f16x4*)(Cp + tx * 4) = p0;
    *(f16x4*)(Cp + 64 + tx * 4) = p1;
  }
}

// ---------------------------------------------------------------------------
// FUSED kernel: 256 blocks x 768 threads.
//  blocks 0..63: systolic LSTM (round-5 dataflow + tag-in-payload protocol,
//    VERBATIM — measured 124us/dispatch, verified absmax 1.9e-6). This is the
//    session's verified optimum configuration (round 7, 26.57 ms total).
//  blocks 64..255: GEMM for next chunk at lo_g; 3 sub-tiles/block.
// ---------------------------------------------------------------------------
#define HSTR 784   // padded h2s row stride in bytes (768 data + 16 pad)

union FusedSh {
  struct { char h2s[16 * HSTR]; unsigned pub[16 * 25]; } L;    // 12544+1600 B
  struct { f16x2 As2[3][8 * 136]; f16x2 Bs2[3][8 * 128]; } G;  // 25344 B
  char pad[25600];
};

__global__ __launch_bounds__(768, 1) void fused_kernel(
    const f16* __restrict__ xgc_rd, f16* __restrict__ xgc_wr,
    const f16* __restrict__ whB, const float* __restrict__ bias,
    f16* __restrict__ act, float* __restrict__ cst, const float* __restrict__ Wi,
    unsigned* __restrict__ xh,
    int lo_l, int lo_g, int reverse, int first, int do_gemm, int epoch) {
  __shared__ FusedSh sh;
  int tid = threadIdx.x;

  if (blockIdx.x < NLB) {
    // ================= systolic LSTM branch (MFMA) =================
    int wid = blockIdx.x;
    int g = wid & 7;             // group 0..7 (16 batches)
    int isl = wid >> 3;          // column slice 0..7 (48 h-cols)
    int b0 = g * 16;
    int nt = tid >> 6;           // wave id == N-tile 0..11
    int l = tid & 63;
    int bg = l >> 4;             // C-frag row group: batches bg*4..bg*4+3
    int qj = (l >> 2) & 3;       // jj offset within tile
    int gate = l & 3;
    int jj = nt * 4 + qj;        // 0..47
    int hcol = isl * 48 + jj;
    int gcol = gate * 384 + isl * 48 + jj;

    // --- B-frag weights -> 48 VGPRs, loaded once, pinned ---
    f16x8 wreg[12];
    {
      const f16x8* wp = (const f16x8*)whB + (size_t)(isl * 12 + nt) * 12 * 64 + l;
#pragma unroll
      for (int ks = 0; ks < 12; ++ks) wreg[ks] = wp[(size_t)ks * 64];
#pragma unroll
      for (int ks = 0; ks < 12; ++ks) asm volatile("" : "+v"(wreg[ks]));
    }
    float bias_own = bias[gcol];

    float c_reg[4];
    if (first) {
#pragma unroll
      for (int r = 0; r < 4; ++r) c_reg[r] = 0.f;
      for (int i = tid; i < 16 * HSTR / 16; i += 768)
        *(f16x8*)(sh.L.h2s + i * 16) = (f16x8){};
    } else {
      int tprev = reverse ? (lo_l + TC) : (lo_l - 1);
#pragma unroll
      for (int r = 0; r < 4; ++r)
        c_reg[r] = cst[(size_t)(b0 + bg * 4 + r) * HDIM + hcol];
      int flat = tid * 8;
      int bt = flat / 384, c0 = flat % 384;
      *(f16x8*)(sh.L.h2s + bt * HSTR + c0 * 2) =
          *(const f16x8*)(act + ((size_t)(b0 + bt) * T_OUT + tprev) * HDIM + c0);
    }
    __syncthreads();

    const char* arow = sh.L.h2s + (l & 15) * HSTR + (l >> 4) * 16;
    unsigned short* pubh = (unsigned short*)sh.L.pub;

    // second gather unit (1024 units over 768 threads, spread across waves)
    int k2 = (tid % 3 == 0) ? (768 + tid / 3) : -1;

    // xg preload for step 0
    float xv[4];
    {
      int tl0 = reverse ? (TC - 1) : 0;
      const f16* xb = xgc_rd + ((size_t)(b0 + bg * 4) * TC + tl0) * GDIM + gcol;
#pragma unroll
      for (int r = 0; r < 4; ++r) xv[r] = (float)xb[(size_t)r * TC * GDIM];
    }

    for (int s = 0; s < TC; ++s) {
      int t = reverse ? (lo_l + TC - 1 - s) : (lo_l + s);

      // --- z = h @ Wslice via MFMA (full K per wave, no reduction) ---
      f32x4 acc = {0.f, 0.f, 0.f, 0.f};
#pragma unroll
      for (int ks = 0; ks < 12; ++ks) {
        f16x8 a = *(const f16x8*)(arow + ks * 64);
        acc = __builtin_amdgcn_mfma_f32_16x16x32_f16(a, wreg[ks], acc, 0, 0, 0);
      }

      // --- gates: quad butterfly distributes all 4 gates of (jj, 4 batches) ---
      f16 h16[4];
#pragma unroll
      for (int r = 0; r < 4; ++r) {
        float a = acc[r] + xv[r] + bias_own;
        float b = __shfl_xor(a, 1);
        float cc = __shfl_xor(a, 2);
        float dd = __shfl_xor(b, 2);
        float zi = (gate == 0) ? a : (gate == 1) ? b : (gate == 2) ? cc : dd;
        float zf = (gate == 1) ? a : (gate == 0) ? b : (gate == 3) ? cc : dd;
        float zg = (gate == 2) ? a : (gate == 3) ? b : (gate == 0) ? cc : dd;
        float zo = (gate == 3) ? a : (gate == 2) ? b : (gate == 1) ? cc : dd;
        float ig = sigf(zi), fg = sigf(zf), gv = tanh_fast(zg), og = sigf(zo);
        c_reg[r] = fg * c_reg[r] + ig * gv;
        h16[r] = (f16)(og * tanh_fast(c_reg[r]));
      }

      if (s + 1 < TC) {
        unsigned tag = (unsigned)(epoch * TC + s + 1);
        unsigned* slotbase = xh + (size_t)(s & 1) * 128 * 256;

        // --- stage own h slice into LDS pub (rows=batch, 24 pair-words) ---
        if (gate == 0) {
          int lcol = nt * 4 + qj;
#pragma unroll
          for (int r = 0; r < 4; ++r)
            pubh[(bg * 4 + r) * 50 + lcol] = __builtin_bit_cast(unsigned short, h16[r]);
        }
        __syncthreads();  // barrier A: pub staged (MFMA h2s reads also done)

        // --- publish: 128 threads x one 16B unit (3 data words + tag) ---
        if (tid < 128) {
          int bt = tid >> 3, u = tid & 7;
          const unsigned* pw = sh.L.pub + bt * 25 + u * 3;
          u32x4 dnew;
          dnew[0] = pw[0]; dnew[1] = pw[1]; dnew[2] = pw[2]; dnew[3] = tag;
          u32x4* dp = (u32x4*)(slotbase + (((size_t)(b0 + bt) * 64) + isl * 8 + u) * 4);
          asm volatile("global_store_dwordx4 %0, %1, off sc0 sc1"
                       :: "v"(dp), "v"(dnew) : "memory");
        }

        // --- hidden under flight: act store + next-step xg prefetch ---
        if (gate == 0) {
#pragma unroll
          for (int r = 0; r < 4; ++r)
            act[((size_t)(b0 + bg * 4 + r) * T_OUT + t) * HDIM + hcol] = h16[r];
        }
        {
          int tl_n = reverse ? (TC - 2 - s) : (s + 1);
          const f16* xb = xgc_rd + ((size_t)(b0 + bg * 4) * TC + tl_n) * GDIM + gcol;
#pragma unroll
          for (int r = 0; r < 4; ++r) xv[r] = (float)xb[(size_t)r * TC * GDIM];
        }

        // --- poll-gather: tag-checked dwordx4 units -> h2s ---
        const u32x4* upA = nullptr; const u32x4* upB = nullptr;
        unsigned* dstA = nullptr; unsigned* dstB = nullptr;
#pragma unroll
        for (int uu = 0; uu < 2; ++uu) {
          int k = (uu == 0) ? tid : k2;
          if (uu == 1 && k < 0) break;
          int bt = k >> 6, rem = k & 63;
          int isl_src = rem >> 3, u = rem & 7;
          unsigned* dst = (unsigned*)(sh.L.h2s + bt * HSTR + isl_src * 96 + u * 12);
          if (isl_src == isl) {
            const unsigned* pw = sh.L.pub + bt * 25 + u * 3;
            dst[0] = pw[0]; dst[1] = pw[1]; dst[2] = pw[2];
          } else {
            const u32x4* up = (const u32x4*)(slotbase + (((size_t)(b0 + bt) * 64) + rem) * 4);
            if (!upA) { upA = up; dstA = dst; } else { upB = up; dstB = dst; }
          }
        }
        if (upA && !upB) {
          u32x4 v;
          while (true) {
            asm volatile("global_load_dwordx4 %0, %1, off sc0 sc1\n\ts_waitcnt vmcnt(0)"
                         : "=v"(v) : "v"(upA) : "memory");
            if (v[3] >= tag) break;
            __builtin_amdgcn_s_sleep(1);
          }
          dstA[0] = v[0]; dstA[1] = v[1]; dstA[2] = v[2];
        } else if (upA && upB) {
          u32x4 v0, v1;
          while (true) {
            asm volatile("global_load_dwordx4 %0, %2, off sc0 sc1\n\t"
                         "global_load_dwordx4 %1, %3, off sc0 sc1\n\t"
                         "s_waitcnt vmcnt(0)"
                         : "=&v"(v0), "=&v"(v1) : "v"(upA), "v"(upB) : "memory");
            if (v0[3] >= tag && v1[3] >= tag) break;
            __builtin_amdgcn_s_sleep(1);
          }
          dstA[0] = v0[0]; dstA[1] = v0[1]; dstA[2] = v0[2];
          dstB[0] = v1[0]; dstB[1] = v1[1]; dstB[2] = v1[2];
        }
        __syncthreads();  // barrier B: h2s complete for next step
      } else {
        if (gate == 0) {
#pragma unroll
          for (int r = 0; r < 4; ++r)
            act[((size_t)(b0 + bg * 4 + r) * T_OUT + t) * HDIM + hcol] = h16[r];
        }
      }
    }
    if (gate == 0) {
#pragma unroll
      for (int r = 0; r < 4; ++r)
        cst[(size_t)(b0 + bg * 4 + r) * HDIM + hcol] = c_reg[r];
    }
  } else {
    // ================= GEMM worker branch =================
    if (!do_gemm) return;
    int wid = blockIdx.x - NLB;       // 0..191
    int sub = tid >> 8;               // 0..2 (wave-uniform)
    int stid = tid & 255;
    int tileid = wid + 192 * sub;     // 0..575
    bool valid = (tileid < NTILES);
    int tclamp = valid ? tileid : 0;
    int n0 = (tclamp % 12) * 128;
    int m0 = (tclamp / 12) * 128;
    f16x2* As2 = &sh.G.As2[sub][0];
    f16x2* Bs2 = &sh.G.Bs2[sub][0];
    int am = stid >> 2;
    int ak = (stid & 3) * 4;
    int bk = stid >> 5;
    int bn = (stid & 31) * 4;
    int row0 = m0 + am, row1 = row0 + 64;
    const f16* Ap0 = act + ((size_t)(row0 / TC) * T_OUT + lo_g + row0 % TC) * HDIM + ak;
    const f16* Ap1 = act + ((size_t)(row1 / TC) * T_OUT + lo_g + row1 % TC) * HDIM + ak;
    const float* Bp = Wi + (size_t)(2 * bk) * GDIM + n0 + bn;
    f16x4 ra0 = {}, ra1 = {};
    float4 rb0 = {}, rb1 = {};
    if (valid) {
      ra0 = *(const f16x4*)Ap0;
      ra1 = *(const f16x4*)Ap1;
      rb0 = *(const float4*)Bp;
      rb1 = *(const float4*)(Bp + (size_t)GDIM);
    }
    float acc[8][8];
#pragma unroll
    for (int i = 0; i < 8; ++i)
#pragma unroll
      for (int j = 0; j < 8; ++j) acc[i][j] = 0.f;
    int tx = stid & 15, ty = stid >> 4;
    for (int kt = 0; kt < 24; ++kt) {
      if (valid) {
        int ak2 = ak >> 1;
        As2[(ak2 + 0) * 136 + am] = (f16x2){ra0[0], ra0[1]};
        As2[(ak2 + 1) * 136 + am] = (f16x2){ra0[2], ra0[3]};
        As2[(ak2 + 0) * 136 + am + 64] = (f16x2){ra1[0], ra1[1]};
        As2[(ak2 + 1) * 136 + am + 64] = (f16x2){ra1[2], ra1[3]};
        Bs2[bk * 128 + bn + 0] = (f16x2){(f16)rb0.x, (f16)rb1.x};
        Bs2[bk * 128 + bn + 1] = (f16x2){(f16)rb0.y, (f16)rb1.y};
        Bs2[bk * 128 + bn + 2] = (f16x2){(f16)rb0.z, (f16)rb1.z};
        Bs2[bk * 128 + bn + 3] = (f16x2){(f16)rb0.w, (f16)rb1.w};
      }
      __syncthreads();
      if (valid) {
        if (kt < 23) {
          Ap0 += 16; Ap1 += 16; Bp += (size_t)16 * GDIM;
          ra0 = *(const f16x4*)Ap0;
          ra1 = *(const f16x4*)Ap1;
          rb0 = *(const float4*)Bp;
          rb1 = *(const float4*)(Bp + (size_t)GDIM);
        }
#pragma unroll
        for (int k2i = 0; k2i < 8; ++k2i) {
          f16x8 a0 = *(const f16x8*)&As2[k2i * 136 + ty * 4];
          f16x8 a1 = *(const f16x8*)&As2[k2i * 136 + 64 + ty * 4];
          f16x8 b0 = *(const f16x8*)&Bs2[k2i * 128 + tx * 4];
          f16x8 b1 = *(const f16x8*)&Bs2[k2i * 128 + 64 + tx * 4];
          f16x2 av[8], bv[8];
#pragma unroll
          for (int qq = 0; qq < 4; ++qq) {
            av[qq] = (f16x2){a0[2 * qq], a0[2 * qq + 1]};
            av[qq + 4] = (f16x2){a1[2 * qq], a1[2 * qq + 1]};
            bv[qq] = (f16x2){b0[2 * qq], b0[2 * qq + 1]};
            bv[qq + 4] = (f16x2){b1[2 * qq], b1[2 * qq + 1]};
          }
#pragma unroll
          for (int i = 0; i < 8; ++i)
#pragma unroll
            for (int j = 0; j < 8; ++j) acc[i][j] = fdot2(av[i], bv[j], acc[i][j]);
        }
      }
      __syncthreads();
    }
    if (valid) {
#pragma unroll
      for (int i = 0; i < 8; ++i) {
        int mi = (i < 4) ? (ty * 4 + i) : (64 + ty * 4 + i - 4);
        f16* Cp = xgc_wr + (size_t)(m0 + mi) * GDIM + n0;
        f16x4 p0, p1;
        p0[0] = (f16)acc[i][0]; p0[1] = (f16)acc[i][1]; p0[2] = (f16)acc[i][2]; p0[3] = (f16)acc[i][3];
        p1[0] = (f16)acc[i][4]; p1[1] = (f16)acc[i][5]; p1[2] = (f16)acc[i][6]; p1[3] = (f16)acc[i][7];
        *(f16x4*)(Cp + tx * 4) = p0;
        *(f16x4*)(Cp + 64 + tx * 4) = p1;
      }
    }
  }
}

// ---------------------------------------------------------------------------
// dense: out(204800,5) = h(204800,384 fp16) @ W(384,5) + b  (fp32 out)
// ---------------------------------------------------------------------------
__global__ __launch_bounds__(256) void dense_kernel(
    const f16* __restrict__ h, const float* __restrict__ dw,
    const float* __restrict__ db, float* __restrict__ out) {
  __shared__ float ws_[1920];
  __shared__ float bs[5];
  int tid = threadIdx.x;
  for (int i = tid; i < 1920; i += 256) ws_[i] = dw[i];
  if (tid < 5) bs[tid] = db[tid];
  __syncthreads();
  size_t flat = (size_t)blockIdx.x * 256 + tid;
  const f16* hp = h + flat * HDIM;
  float acc[5];
#pragma unroll
  for (int o = 0; o < 5; ++o) acc[o] = bs[o];
  for (int d = 0; d < HDIM; d += 4) {
    f16x4 hv = *(const f16x4*)(hp + d);
#pragma unroll
    for (int o = 0; o < 5; ++o) {
      acc[o] = fmaf((float)hv[0], ws_[(d + 0) * 5 + o], acc[o]);
      acc[o] = fmaf((float)hv[1], ws_[(d + 1) * 5 + o], acc[o]);
      acc[o] = fmaf((float)hv[2], ws_[(d + 2) * 5 + o], acc[o]);
      acc[o] = fmaf((float)hv[3], ws_[(d + 3) * 5 + o], acc[o]);
    }
  }
  float* op = out + flat * 5;
#pragma unroll
  for (int o = 0; o < 5; ++o) op[o] = acc[o];
}

// ---------------------------------------------------------------------------
extern "C" void kernel_launch(void* const* d_in, const int* in_sizes, int n_in,
                              void* d_out, int out_size, void* d_ws, size_t ws_size,
                              hipStream_t stream) {
  const float* x  = (const float*)d_in[0];
  const float* w1 = (const float*)d_in[1];
  const float* b1 = (const float*)d_in[2];
  const float* w2 = (const float*)d_in[3];
  const float* b2 = (const float*)d_in[4];
  const float* w3 = (const float*)d_in[5];
  const float* b3 = (const float*)d_in[6];
  const float* Wi = (const float*)d_in[7];
  const float* Wh = (const float*)d_in[8];
  const float* lb = (const float*)d_in[9];
  const float* dw = (const float*)d_in[10];
  const float* db = (const float*)d_in[11];
  float* out = (float*)d_out;
  char* ws = (char*)d_ws;

  // ws (~195.4 MB <= proven 197): act | xgcA | xgcB | whB | cst | xh | w3t
  const size_t ACT_BYTES = (size_t)B_SZ * T_OUT * HDIM * 2;   // 157.3 MB
  const size_t XGC_BYTES = (size_t)B_SZ * TC * GDIM * 2;      // 15.7 MB each
  const size_t WHB_BYTES = (size_t)5 * 8 * 12 * 12 * 64 * 16; // 5.9 MB
  const size_t CST_BYTES = (size_t)B_SZ * HDIM * 4;           // 196.6 KB
  const size_t XH_BYTES  = (size_t)2 * 128 * 64 * 16;         // 256 KB
  const size_t W3T_BYTES = (size_t)384 * 320 * 2;             // 240 KB
  f16*      act  = (f16*)ws;
  f16*      xgcA = (f16*)(ws + ACT_BYTES);
  f16*      xgcB = (f16*)(ws + ACT_BYTES + XGC_BYTES);
  f16*      whB  = (f16*)(ws + ACT_BYTES + 2 * XGC_BYTES);
  float*    cst  = (float*)(ws + ACT_BYTES + 2 * XGC_BYTES + WHB_BYTES);
  unsigned* xh   = (unsigned*)(ws + ACT_BYTES + 2 * XGC_BYTES + WHB_BYTES + CST_BYTES);
  f16*      w3t  = (f16*)(ws + ACT_BYTES + 2 * XGC_BYTES + WHB_BYTES + CST_BYTES + XH_BYTES);
  f16* y2 = xgcA;  // alias: consumed before xgc/whB are written

  hipMemsetAsync(xh, 0, XH_BYTES, stream);  // zero tags (monotonic from 1)

  hipLaunchKernelGGL(conv12_kernel, dim3(B_SZ * T_IN / 256), dim3(256), 0, stream,
                     x, w1, b1, w2, b2, y2);
  hipLaunchKernelGGL(w3cvt_kernel, dim3(384 * 320 / 256), dim3(256), 0, stream,
                     w3, w3t);
  hipLaunchKernelGGL(conv3_kernel, dim3(T_OUT / C3M, B_SZ), dim3(384), 0, stream,
                     y2, w3t, b3, act);
  hipLaunchKernelGGL(whcvt_kernel, dim3((unsigned)(WHB_BYTES / 4 / 256)), dim3(256), 0, stream,
                     Wh, (f16x2*)whB);

  for (int l = 0; l < 5; ++l) {
    int rev = (l % 2 == 0) ? 1 : 0;
    const float* wi_p = Wi + (size_t)l * HDIM * GDIM;
    const f16* wh_p = whB + (size_t)l * 8 * 12 * 12 * 64 * 8;
    const float* lb_p = lb + (size_t)l * GDIM;
    int lo0 = rev ? (T_OUT - TC) : 0;
    hipLaunchKernelGGL(gemm_xg_kernel, dim3(GDIM / 128, (B_SZ * TC) / 128), dim3(256), 0, stream,
                       act, wi_p, xgcA, lo0);
    for (int ci = 0; ci < NCHUNK; ++ci) {
      int lo_l = rev ? (T_OUT - (ci + 1) * TC) : (ci * TC);
      int do_gemm = (ci + 1 < NCHUNK) ? 1 : 0;
      int lo_g = do_gemm ? (rev ? (T_OUT - (ci + 2) * TC) : ((ci + 1) * TC)) : 0;
      f16* rd = (ci % 2 == 0) ? xgcA : xgcB;
      f16* wr = (ci % 2 == 0) ? xgcB : xgcA;
      int epoch = l * NCHUNK + ci;
      hipLaunchKernelGGL(fused_kernel, dim3(256), dim3(768), 0, stream,
                         rd, wr, wh_p, lb_p, act, cst, wi_p, xh,
                         lo_l, lo_g, rev, (ci == 0) ? 1 : 0, do_gemm, epoch);
    }
  }
  hipLaunchKernelGGL(dense_kernel, dim3((B_SZ * T_OUT) / 256), dim3(256), 0, stream,
                     act, dw, db, out);
}